// Round 1
// baseline (628.404 us; speedup 1.0000x reference)
//
#include <hip/hip_runtime.h>

constexpr int N_NODES = 100000;
constexpr int N_EDGES = 1600000;
constexpr int N_CLUST = 25000;
constexpr int N_GRAPH = 64;
constexpr int NCLSN   = 10;

// bucket decomposition for the radix node-CSR build
constexpr int BKT1_SHIFT = 9;                       // node-dst buckets of 512 ids
constexpr int NBKT1 = (N_NODES + 511) / 512;        // 196
constexpr int EPB = 4096;                           // edges per block (count/scatter)
constexpr int NEB = (N_EDGES + EPB - 1) / EPB;      // 391
constexpr int SORT_CAP = 12288;                     // LDS staging cap (mean 8163, sd ~90)

// edge payload layout (esrc1 / psrcC): bits [16:0] = src id, bits [20:17] = dst & 15
// (dst-local row index within a 16-aligned MFMA group; conv_mfma consumes this)
constexpr unsigned PAY_SRC_MASK = 0x1FFFFu;

// scan partitioning: 1024 elements per block, three concatenated segments
constexpr int SCAN_BPB = 1024;
constexpr int NB1 = (N_NODES + SCAN_BPB - 1) / SCAN_BPB;  // 98
constexpr int NB2 = (N_CLUST + SCAN_BPB - 1) / SCAN_BPB;  // 25
constexpr int NB3 = (N_CLUST + SCAN_BPB - 1) / SCAN_BPB;  // 25
constexpr int NBT = NB1 + NB2 + NB3;                      // 148

// ---- bf16 pack/unpack helpers (features stored as packed pairs in uint) ----
__device__ __forceinline__ float bf16lo(unsigned u){ return __uint_as_float(u << 16); }
__device__ __forceinline__ float bf16hi(unsigned u){ return __uint_as_float(u & 0xffff0000u); }
__device__ __forceinline__ unsigned bf16_rne(float f){
  unsigned u = __float_as_uint(f);
  return (u + 0x7fffu + ((u >> 16) & 1u)) >> 16;
}
__device__ __forceinline__ unsigned pack2(float lo, float hi){
  return bf16_rne(lo) | (bf16_rne(hi) << 16);
}

typedef short bf16x8 __attribute__((ext_vector_type(8)));
typedef float f32x4  __attribute__((ext_vector_type(4)));

// ---------------------------------------------------------------------------
// radix node-CSR build, phase 1: per-block bucket histograms (no global atomics)
// ---------------------------------------------------------------------------
__launch_bounds__(1024)
__global__ void count_kernel(const int* __restrict__ ei, int* __restrict__ bhist){
  __shared__ int h1c[NBKT1];
  int t = threadIdx.x;
  for (int i = t; i < NBKT1; i += 1024) h1c[i] = 0;
  __syncthreads();
  int e0 = blockIdx.x * EPB;
  #pragma unroll
  for (int i = 0; i < EPB / 1024; ++i){
    int e = e0 + i * 1024 + t;
    if (e < N_EDGES) atomicAdd(&h1c[ei[N_EDGES + e] >> BKT1_SHIFT], 1);
  }
  __syncthreads();
  for (int i = t; i < NBKT1; i += 1024) bhist[blockIdx.x * NBKT1 + i] = h1c[i];
}

// phase 2a: column scan of the histogram matrix -> per-(block,bucket) offsets
__launch_bounds__(512)
__global__ void colscan(const int* __restrict__ bhist, int* __restrict__ boffs,
                        int* __restrict__ gcnt1){
  __shared__ int s[512];
  int i = blockIdx.x;                 // bucket
  int t = threadIdx.x;                // edge-block index
  int v = (t < NEB) ? bhist[t * NBKT1 + i] : 0;
  s[t] = v; __syncthreads();
  for (int o = 1; o < 512; o <<= 1){
    int a = (t >= o) ? s[t - o] : 0;
    __syncthreads(); s[t] += a; __syncthreads();
  }
  if (t < NEB) boffs[t * NBKT1 + i] = s[t] - v;   // exclusive within column
  if (t == 511) gcnt1[i] = s[511];
}

// phase 2b: bucket bases (prefix over 196 totals)
__launch_bounds__(256)
__global__ void bucket_scan(const int* __restrict__ gcnt1, int* __restrict__ gbase1){
  __shared__ int s[256];
  int t = threadIdx.x;
  int v = (t < NBKT1) ? gcnt1[t] : 0;
  s[t] = v; __syncthreads();
  for (int off = 1; off < 256; off <<= 1){
    int a = (t >= off) ? s[t - off] : 0;
    __syncthreads(); s[t] += a; __syncthreads();
  }
  if (t < NBKT1) gbase1[t] = s[t] - v;
}

// phase 3: single-pass scatter into pre-reserved runs (no global atomics)
__launch_bounds__(1024)
__global__ void scatter_kernel(const int* __restrict__ ei, const int* __restrict__ gbase1,
                               const int* __restrict__ boffs, unsigned int* __restrict__ stage1){
  __shared__ int gb1[NBKT1];
  __shared__ int cur[NBKT1];
  int t = threadIdx.x, b = blockIdx.x;
  for (int i = t; i < NBKT1; i += 1024){
    gb1[i] = gbase1[i] + boffs[b * NBKT1 + i];
    cur[i] = 0;
  }
  __syncthreads();
  int e0 = b * EPB;
  #pragma unroll
  for (int i = 0; i < EPB / 1024; ++i){
    int e = e0 + i * 1024 + t;
    if (e < N_EDGES){
      int src = ei[e], dst = ei[N_EDGES + e];
      int bk = dst >> BKT1_SHIFT;
      int r = atomicAdd(&cur[bk], 1);
      stage1[gb1[bk] + r] = ((unsigned)(dst & 511) << 17) | (unsigned)src;
    }
  }
}

// phase 4: per-bucket LDS counting sort + coalesced degree writes (1024 thr)
// payload keeps bits [20:17] = dst & 15 for the MFMA conv's one-hot build
__launch_bounds__(1024)
__global__ void bucket_sort(const unsigned int* __restrict__ stage, const int* __restrict__ gbase,
                            const int* __restrict__ gcnt, int* __restrict__ outpay,
                            int* __restrict__ deg){
  __shared__ int cnt[512], off[512];
  __shared__ int sorted[SORT_CAP];
  int b = blockIdx.x, t = threadIdx.x;
  int base = gbase[b], n = gcnt[b];
  if (t < 512) cnt[t] = 0;
  __syncthreads();
  for (int i = t; i < n; i += 1024) atomicAdd(&cnt[stage[base + i] >> 17], 1);
  __syncthreads();
  if (t < 512){
    int idx = b * 512 + t;
    if (idx < N_NODES) deg[idx] = cnt[t];
    off[t] = cnt[t];
  }
  __syncthreads();
  for (int s = 1; s < 512; s <<= 1){
    int v = 0;
    if (t < 512 && t >= s) v = off[t - s];
    __syncthreads();
    if (t < 512) off[t] += v;
    __syncthreads();
  }
  if (t < 512) off[t] -= cnt[t];       // exclusive cursors
  __syncthreads();
  if (n <= SORT_CAP){
    for (int i = t; i < n; i += 1024){
      unsigned w = stage[base + i];
      int r = atomicAdd(&off[w >> 17], 1);
      sorted[r] = (int)(w & 0x1FFFFFu);   // src | (dst&15)<<17
    }
    __syncthreads();
    for (int i = t; i < n; i += 1024) outpay[base + i] = sorted[i];
  } else {  // never expected; correct fallback
    for (int i = t; i < n; i += 1024){
      unsigned w = stage[base + i];
      int r = atomicAdd(&off[w >> 17], 1);
      outpay[base + r] = (int)(w & 0x1FFFFFu);
    }
  }
}

// per-node: cluster membership count + cluster in-degree (sum of member deg1)
__global__ void node_prep(const int* __restrict__ cluster, const int* __restrict__ deg1,
                          int* __restrict__ cntn, int* __restrict__ deg2){
  int v = blockIdx.x * blockDim.x + threadIdx.x;
  if (v < N_NODES){
    int c = cluster[v];
    atomicAdd(&cntn[c], 1);
    atomicAdd(&deg2[c], deg1[v]);
  }
}

// ---------------------------------------------------------------------------
// device-wide 3-segment exclusive scan
// ---------------------------------------------------------------------------
__device__ __forceinline__ void seg_select(int b, const int* deg1, const int* cntn,
                                           const int* deg2, const int*& src, int& n, int& base){
  if (b < NB1){ src = deg1; n = N_NODES; base = b * SCAN_BPB; }
  else if (b < NB1 + NB2){ src = cntn; n = N_CLUST; base = (b - NB1) * SCAN_BPB; }
  else { src = deg2; n = N_CLUST; base = (b - NB1 - NB2) * SCAN_BPB; }
}

__launch_bounds__(256)
__global__ void block_sums(const int* __restrict__ deg1, const int* __restrict__ cntn,
                           const int* __restrict__ deg2, int* __restrict__ bsum){
  int b = blockIdx.x;
  const int* src; int n, base;
  seg_select(b, deg1, cntn, deg2, src, n, base);
  int t = threadIdx.x;
  int i0 = base + t * 4;
  int s = 0;
  if (i0 + 3 < n){ int4 v = *(const int4*)&src[i0]; s = v.x + v.y + v.z + v.w; }
  else { for (int j = 0; j < 4; ++j){ int i = i0 + j; if (i < n) s += src[i]; } }
  __shared__ int sh[256];
  sh[t] = s; __syncthreads();
  for (int off = 128; off > 0; off >>= 1){
    if (t < off) sh[t] += sh[t + off];
    __syncthreads();
  }
  if (t == 0) bsum[b] = sh[0];
}

__launch_bounds__(256)
__global__ void scan_bsums(const int* __restrict__ bsum, int* __restrict__ boff,
                           int* __restrict__ rowptr1, int* __restrict__ rowptrn,
                           int* __restrict__ rowptr2){
  __shared__ int s[256];
  int t = threadIdx.x;
  int v = (t < NBT) ? bsum[t] : 0;
  s[t] = v; __syncthreads();
  int seg = (t < NB1) ? 0 : (t < NB1 + NB2 ? 1 : 2);
  for (int off = 1; off < 256; off <<= 1){
    int add = 0;
    if (t >= off){
      int u = t - off;
      int useg = (u < NB1) ? 0 : (u < NB1 + NB2 ? 1 : 2);
      if (useg == seg) add = s[u];
    }
    __syncthreads();
    s[t] += add;
    __syncthreads();
  }
  if (t < NBT) boff[t] = s[t] - v;
  if (t == NB1 - 1)       rowptr1[N_NODES] = s[t];
  if (t == NB1 + NB2 - 1) rowptrn[N_CLUST] = s[t];
  if (t == NBT - 1)       rowptr2[N_CLUST] = s[t];
}

__launch_bounds__(256)
__global__ void scan_final(const int* __restrict__ deg1, const int* __restrict__ cntn,
                           const int* __restrict__ deg2, const int* __restrict__ boff,
                           int* __restrict__ rowptr1, float* __restrict__ dis1,
                           int* __restrict__ rowptrn, int* __restrict__ curn,
                           int* __restrict__ rowptr2, float* __restrict__ dis2){
  int b = blockIdx.x;
  const int* src; int n, base;
  seg_select(b, deg1, cntn, deg2, src, n, base);
  int* rp; int* cur; float* dis;
  if (b < NB1){ rp = rowptr1; cur = nullptr; dis = dis1; }
  else if (b < NB1 + NB2){ rp = rowptrn; cur = curn; dis = nullptr; }
  else { rp = rowptr2; cur = nullptr; dis = dis2; }
  int t = threadIdx.x;
  int i0 = base + t * 4;
  int v[4]; int s = 0;
  #pragma unroll
  for (int j = 0; j < 4; ++j){ int i = i0 + j; v[j] = (i < n) ? src[i] : 0; s += v[j]; }
  __shared__ int sh[256];
  sh[t] = s; __syncthreads();
  for (int off = 1; off < 256; off <<= 1){
    int add = (t >= off) ? sh[t - off] : 0;
    __syncthreads();
    sh[t] += add;
    __syncthreads();
  }
  int run = sh[t] - s + boff[b];
  #pragma unroll
  for (int j = 0; j < 4; ++j){
    int i = i0 + j;
    if (i < n){
      rp[i] = run;
      if (cur) cur[i] = run;
      if (dis) dis[i] = rsqrtf((float)v[j] + 1.0f);
      run += v[j];
    }
  }
}

// node->cluster CSR fill
__global__ void fill_n(const int* __restrict__ cluster, int* __restrict__ curn,
                       int* __restrict__ nidx){
  int v = blockIdx.x * blockDim.x + threadIdx.x;
  if (v >= N_NODES) return;
  nidx[atomicAdd(&curn[cluster[v]], 1)] = v;
}

// ---------------------------------------------------------------------------
// psrcC build: cluster c's pooled-edge list = concat of members' edge runs
// payload: src-cluster | (dst-cluster & 15) << 17
// ---------------------------------------------------------------------------
__launch_bounds__(256)
__global__ void psrc_build(const int* __restrict__ rowptrn, const int* __restrict__ nidx,
                           const int* __restrict__ rowptr1, const int* __restrict__ esrc1,
                           const int* __restrict__ cluster, const int* __restrict__ rowptr2,
                           int* __restrict__ psrcC){
  int c = blockIdx.x * 4 + (threadIdx.x >> 6);
  int l = threadIdx.x & 63;
  int mb = rowptrn[c], me = rowptrn[c + 1];
  int cnt = me - mb;                       // members per cluster (<= 64)
  int base_l = 0, d_l = 0;
  if (l < cnt){
    int v = nidx[mb + l];
    base_l = rowptr1[v];
    d_l = rowptr1[v + 1] - base_l;
  }
  int pref = d_l;                          // inclusive scan over 64 lanes
  #pragma unroll
  for (int off = 1; off < 64; off <<= 1){
    int u = __shfl_up(pref, off);
    if (l >= off) pref += u;
  }
  int total = __shfl(pref, 63);
  int wbase = rowptr2[c];
  int dbits = (c & 15) << 17;
  int iters = (total + 63) >> 6;           // uniform loop; all lanes active
  for (int k = 0; k < iters; ++k){
    int idx = k * 64 + l;
    int idxc = min(idx, total - 1);
    int m = 0;
    for (int j = 0; j < cnt; ++j){
      int pj = __shfl(pref, j);
      if (idxc >= pj) m = j + 1;
    }
    int pm = __shfl(pref, m);
    int dm = __shfl(d_l, m);
    int bm = __shfl(base_l, m);
    int e = bm + idxc - (pm - dm);
    int sc = cluster[esrc1[e] & (int)PAY_SRC_MASK];
    if (idx < total) psrcC[wbase + idx] = sc | dbits;
  }
}

// ---------------------------------------------------------------------------
// MFMA GEMM: C[M,128] = (A[M,128] @ B[128,128]) * scale[row], bf16 packed out
// ---------------------------------------------------------------------------
template<bool A_BF16>
__launch_bounds__(256)
__global__ void gemm_mfma(const void* __restrict__ Aptr, const float* __restrict__ B,
                          const float* __restrict__ scale, unsigned* __restrict__ Cmat,
                          int M){
  __shared__ __align__(16) unsigned Blds[128 * 68];
  __shared__ __align__(16) unsigned Alds[64 * 68];
  const int t = threadIdx.x;
  const int row0 = blockIdx.x * 64;

  #pragma unroll
  for (int i = 0; i < 8; ++i){
    int task = t + i * 256;
    int kp = task >> 5, nq = task & 31;
    float4 b0 = *(const float4*)&B[(2 * kp) * 128 + nq * 4];
    float4 b1 = *(const float4*)&B[(2 * kp + 1) * 128 + nq * 4];
    Blds[(nq * 4 + 0) * 68 + kp] = pack2(b0.x, b1.x);
    Blds[(nq * 4 + 1) * 68 + kp] = pack2(b0.y, b1.y);
    Blds[(nq * 4 + 2) * 68 + kp] = pack2(b0.z, b1.z);
    Blds[(nq * 4 + 3) * 68 + kp] = pack2(b0.w, b1.w);
  }
  if (A_BF16){
    const unsigned* A = (const unsigned*)Aptr;
    #pragma unroll
    for (int i = 0; i < 8; ++i){
      int idx = t + i * 256;
      int row = idx >> 5, c2 = idx & 31;
      int grow = min(row0 + row, M - 1);
      uint2 v = *(const uint2*)&A[(size_t)grow * 64 + c2 * 2];
      Alds[row * 68 + c2 * 2]     = v.x;
      Alds[row * 68 + c2 * 2 + 1] = v.y;
    }
  } else {
    const float* A = (const float*)Aptr;
    #pragma unroll
    for (int i = 0; i < 8; ++i){
      int idx = t + i * 256;
      int row = idx >> 5, k4 = idx & 31;
      int grow = min(row0 + row, M - 1);
      float4 v = *(const float4*)&A[(size_t)grow * 128 + k4 * 4];
      Alds[row * 68 + k4 * 2]     = pack2(v.x, v.y);
      Alds[row * 68 + k4 * 2 + 1] = pack2(v.z, v.w);
    }
  }
  __syncthreads();

  const int wv = t >> 6, l = t & 63, quad = l >> 4, n16 = l & 15;
  f32x4 acc[8];
  #pragma unroll
  for (int nt = 0; nt < 8; ++nt) acc[nt] = (f32x4){0.f, 0.f, 0.f, 0.f};
  const int arow = wv * 16 + n16;
  #pragma unroll
  for (int ks = 0; ks < 4; ++ks){
    bf16x8 af = *(const bf16x8*)&Alds[arow * 68 + ks * 16 + quad * 4];
    #pragma unroll
    for (int nt = 0; nt < 8; ++nt){
      bf16x8 bfr = *(const bf16x8*)&Blds[(nt * 16 + n16) * 68 + ks * 16 + quad * 4];
      acc[nt] = __builtin_amdgcn_mfma_f32_16x16x32_bf16(af, bfr, acc[nt], 0, 0, 0);
    }
  }
  #pragma unroll
  for (int nt = 0; nt < 8; ++nt){
    #pragma unroll
    for (int r = 0; r < 4; ++r){
      int row = row0 + wv * 16 + quad * 4 + r;
      float sc = scale[min(row, M - 1)];
      float v = acc[nt][r] * sc;
      float vhi = __shfl_xor(v, 1);
      if (((l & 1) == 0) && row < M)
        Cmat[(size_t)row * 64 + nt * 8 + (n16 >> 1)] = pack2(v, vhi);
    }
  }
}

// ---------------------------------------------------------------------------
// MFMA CSR conv: one wave per 16 consecutive dst rows.
// Per 32-edge chunk: gather src rows -> LDS (transposed by feature via
// v_perm), build one-hot A[16x32] from payload bits [20:17], accumulate
//   acc += Onehot . Feat  with mfma_f32_16x16x32_bf16.
// Self-loop handled as 16 appended virtual edges (weight 1), so
//   out = relu(dis[row] * (sum_e Ts[src] + Ts[row]) + b)  -- same algebra as
// the old conv_csr. No __syncthreads: each wave owns a private LDS tile.
// ---------------------------------------------------------------------------
constexpr int BSTR = 17;   // LDS uints per feature row (odd -> banks spread)

__launch_bounds__(256, 4)
__global__ void conv_mfma(const unsigned* __restrict__ Ts, const float* __restrict__ dis,
                          const int* __restrict__ rowptr, const int* __restrict__ epay,
                          const float* __restrict__ bias, unsigned* __restrict__ Hout,
                          int M){
  __shared__ unsigned Blds[4][128 * BSTR];
  const int t = threadIdx.x, wv = t >> 6, l = t & 63;
  const int gi = blockIdx.x * 4 + wv;
  const int base = gi * 16;
  if (base >= M) return;
  const int n16 = l & 15, quad = l >> 4;
  const int beg = rowptr[base];
  const int end = rowptr[min(base + 16, M)];
  const int cnt = end - beg;
  const int selfN = min(16, M - base);
  const int total = cnt + selfN;
  const int nch = (total + 31) >> 5;
  unsigned* Bl = &Blds[wv][0];

  f32x4 acc[8];
  #pragma unroll
  for (int nt = 0; nt < 8; ++nt) acc[nt] = (f32x4){0.f, 0.f, 0.f, 0.f};
  float bv[8];
  #pragma unroll
  for (int nt = 0; nt < 8; ++nt) bv[nt] = bias[nt * 16 + n16];

  for (int ch = 0; ch < nch; ++ch){
    // edge meta for this chunk: lane k (k = l&31) holds edge ch*32+k
    int ke = ch * 32 + (l & 31);
    int d, src;
    if (ke < cnt){
      int p = epay[beg + ke];
      src = p & (int)PAY_SRC_MASK;
      d = (p >> 17) & 15;
    } else {
      int sd = ke - cnt;
      d   = (sd < selfN) ? sd : 31;          // 31 never matches a row -> weight 0
      src = (sd < selfN) ? (base + sd) : 0;  // safe dummy row for OOB lanes
    }
    // stage 32 gathered rows into LDS as [feat][edge-pair] uints
    // (uint at [f][pp] = bf16(edge 2pp, f) | bf16(edge 2pp+1, f) << 16)
    #pragma unroll
    for (int i = 0; i < 4; ++i){
      int pp = quad + i * 4;
      int s0 = __shfl(src, 2 * pp);
      int s1 = __shfl(src, 2 * pp + 1);
      uint4 u0 = *(const uint4*)&Ts[(size_t)s0 * 64 + n16 * 4];
      uint4 u1 = *(const uint4*)&Ts[(size_t)s1 * 64 + n16 * 4];
      unsigned* wp = Bl + (n16 * 8) * BSTR + pp;
      wp[0 * BSTR] = __builtin_amdgcn_perm(u1.x, u0.x, 0x05040100u);
      wp[1 * BSTR] = __builtin_amdgcn_perm(u1.x, u0.x, 0x07060302u);
      wp[2 * BSTR] = __builtin_amdgcn_perm(u1.y, u0.y, 0x05040100u);
      wp[3 * BSTR] = __builtin_amdgcn_perm(u1.y, u0.y, 0x07060302u);
      wp[4 * BSTR] = __builtin_amdgcn_perm(u1.z, u0.z, 0x05040100u);
      wp[5 * BSTR] = __builtin_amdgcn_perm(u1.z, u0.z, 0x07060302u);
      wp[6 * BSTR] = __builtin_amdgcn_perm(u1.w, u0.w, 0x05040100u);
      wp[7 * BSTR] = __builtin_amdgcn_perm(u1.w, u0.w, 0x07060302u);
    }
    // one-hot A fragment: lane holds A[row = n16][k = quad*8 + 0..7]
    union { unsigned u[4]; bf16x8 v; } af;
    #pragma unroll
    for (int jj = 0; jj < 4; ++jj){
      int d0 = __shfl(d, quad * 8 + 2 * jj);
      int d1 = __shfl(d, quad * 8 + 2 * jj + 1);
      af.u[jj] = (d0 == n16 ? 0x3F80u : 0u) | (d1 == n16 ? 0x3F800000u : 0u);
    }
    // B fragments + MFMA (B: lane holds B[k = quad*8+0..7][n = nt*16+n16])
    #pragma unroll
    for (int nt = 0; nt < 8; ++nt){
      union { unsigned u[4]; bf16x8 v; } bf;
      const unsigned* rp = Bl + (nt * 16 + n16) * BSTR + quad * 4;
      bf.u[0] = rp[0]; bf.u[1] = rp[1]; bf.u[2] = rp[2]; bf.u[3] = rp[3];
      acc[nt] = __builtin_amdgcn_mfma_f32_16x16x32_bf16(af.v, bf.v, acc[nt], 0, 0, 0);
    }
  }
  // epilogue: C row = base + quad*4 + r, col = nt*16 + n16
  #pragma unroll
  for (int r = 0; r < 4; ++r){
    int row = base + quad * 4 + r;
    float dsc = dis[min(row, M - 1)];
    #pragma unroll
    for (int nt = 0; nt < 8; ++nt){
      float v = fmaxf(fmaf(dsc, acc[nt][r], bv[nt]), 0.f);
      float vhi = __shfl_xor(v, 1);
      if (((l & 1) == 0) && row < M)
        Hout[(size_t)row * 64 + nt * 8 + (n16 >> 1)] = pack2(v, vhi);
    }
  }
}

// cluster mean pool + batch_p, quarter-wave uint4 gather
__launch_bounds__(256)
__global__ void cluster_gather(const unsigned* __restrict__ h1, const int* __restrict__ rowptrn,
                               const int* __restrict__ nidx, const int* __restrict__ batch,
                               unsigned* __restrict__ hp, int* __restrict__ batchp){
  int c = blockIdx.x * 4 + (threadIdx.x >> 6);
  int l = threadIdx.x & 63;
  int q = l & 15, h = l >> 4;
  int mb = rowptrn[c], me = rowptrn[c + 1];
  float acc[8] = {0.f,0.f,0.f,0.f,0.f,0.f,0.f,0.f};
  int vmax = -1;
  for (int base = mb; base < me; base += 64){
    int n = min(64, me - base);
    int vid = nidx[base + min(l, n - 1)];
    if (l < n) vmax = max(vmax, vid);
    int j = 0;
    for (; j + 8 <= n; j += 8){
      int s0 = __shfl(vid, j + h);
      int s1 = __shfl(vid, j + 4 + h);
      uint4 u0 = *(const uint4*)&h1[(size_t)s0 * 64 + q * 4];
      uint4 u1 = *(const uint4*)&h1[(size_t)s1 * 64 + q * 4];
      acc[0] += bf16lo(u0.x); acc[1] += bf16hi(u0.x);
      acc[2] += bf16lo(u0.y); acc[3] += bf16hi(u0.y);
      acc[4] += bf16lo(u0.z); acc[5] += bf16hi(u0.z);
      acc[6] += bf16lo(u0.w); acc[7] += bf16hi(u0.w);
      acc[0] += bf16lo(u1.x); acc[1] += bf16hi(u1.x);
      acc[2] += bf16lo(u1.y); acc[3] += bf16hi(u1.y);
      acc[4] += bf16lo(u1.z); acc[5] += bf16hi(u1.z);
      acc[6] += bf16lo(u1.w); acc[7] += bf16hi(u1.w);
    }
    for (; j < n; j += 4){
      int ei = j + h;
      int s = __shfl(vid, min(ei, n - 1));
      uint4 u = *(const uint4*)&h1[(size_t)s * 64 + q * 4];
      if (ei < n){
        acc[0] += bf16lo(u.x); acc[1] += bf16hi(u.x);
        acc[2] += bf16lo(u.y); acc[3] += bf16hi(u.y);
        acc[4] += bf16lo(u.z); acc[5] += bf16hi(u.z);
        acc[6] += bf16lo(u.w); acc[7] += bf16hi(u.w);
      }
    }
  }
  #pragma unroll
  for (int k = 0; k < 8; ++k){
    acc[k] += __shfl_xor(acc[k], 16);
    acc[k] += __shfl_xor(acc[k], 32);
  }
  #pragma unroll
  for (int off = 32; off > 0; off >>= 1) vmax = max(vmax, __shfl_xor(vmax, off));
  float inv = 1.0f / (float)max(me - mb, 1);
  if (h == 0){
    uint4 o;
    o.x = pack2(acc[0] * inv, acc[1] * inv);
    o.y = pack2(acc[2] * inv, acc[3] * inv);
    o.z = pack2(acc[4] * inv, acc[5] * inv);
    o.w = pack2(acc[6] * inv, acc[7] * inv);
    *(uint4*)&hp[(size_t)c * 64 + q * 4] = o;
  }
  if (l == 0) batchp[c] = (vmax >= 0) ? batch[vmax] : 0;  // batch sorted by node id
}

__global__ void cntp_kernel(const int* __restrict__ batchp, int* __restrict__ cntp){
  int c = blockIdx.x * blockDim.x + threadIdx.x;
  if (c < N_CLUST) atomicAdd(&cntp[batchp[c]], 1);
}

// graph -> cluster CSR: scan cntp (64 entries) + cursor fill
__global__ void scan_cntp(const int* __restrict__ cntp, int* __restrict__ gbasep,
                          int* __restrict__ curp){
  int t = threadIdx.x;                 // 64 threads
  int v = cntp[t];
  int s = v;
  for (int off = 1; off < 64; off <<= 1){
    int u = __shfl_up(s, off);
    if (t >= off) s += u;
  }
  gbasep[t] = s - v; curp[t] = s - v;
  if (t == 63) gbasep[64] = s;
}

__global__ void fill_c(const int* __restrict__ batchp, int* __restrict__ curp,
                       int* __restrict__ cidx){
  int c = blockIdx.x * blockDim.x + threadIdx.x;
  if (c < N_CLUST) cidx[atomicAdd(&curp[batchp[c]], 1)] = c;
}

// ---------------------------------------------------------------------------
__global__ void graph_bounds(const int* __restrict__ batch, int* __restrict__ gstart){
  int g = threadIdx.x;
  if (g > N_GRAPH) return;
  int lo = 0, hi = N_NODES;
  while (lo < hi){ int mid = (lo + hi) >> 1; if (batch[mid] < g) lo = mid + 1; else hi = mid; }
  gstart[g] = lo;
}

__device__ __forceinline__ void atomicMaxPosF(float* addr, float v){
  atomicMax((int*)addr, __float_as_int(v));
}

// pre-pool gather: graph g's rows are contiguous [gstart[g], gstart[g+1])
constexpr int PRE_SPLIT = 8;
__launch_bounds__(256)
__global__ void pre_pool_g(const unsigned* __restrict__ h1, const int* __restrict__ gstart,
                           float* __restrict__ psum, float* __restrict__ pmax){
  int g = blockIdx.x / PRE_SPLIT, sp = blockIdx.x % PRE_SPLIT;
  int t = threadIdx.x, w = t >> 6, l = t & 63;
  int s0 = gstart[g], s1 = gstart[g + 1];
  int n = s1 - s0;
  int per = (n + PRE_SPLIT - 1) / PRE_SPLIT;
  int b0 = s0 + sp * per, b1 = min(b0 + per, s1);
  float2 a0{0.f,0.f}, a1{0.f,0.f}, a2{0.f,0.f}, a3{0.f,0.f};
  float2 mx{0.f,0.f};
  int i = b0 + w;
  for (; i + 12 < b1; i += 16){
    unsigned u0 = h1[(size_t)(i     ) * 64 + l];
    unsigned u1 = h1[(size_t)(i +  4) * 64 + l];
    unsigned u2 = h1[(size_t)(i +  8) * 64 + l];
    unsigned u3 = h1[(size_t)(i + 12) * 64 + l];
    float f0x = bf16lo(u0), f0y = bf16hi(u0);
    float f1x = bf16lo(u1), f1y = bf16hi(u1);
    float f2x = bf16lo(u2), f2y = bf16hi(u2);
    float f3x = bf16lo(u3), f3y = bf16hi(u3);
    a0.x += f0x; a0.y += f0y; a1.x += f1x; a1.y += f1y;
    a2.x += f2x; a2.y += f2y; a3.x += f3x; a3.y += f3y;
    mx.x = fmaxf(fmaxf(mx.x, fmaxf(f0x, f1x)), fmaxf(f2x, f3x));
    mx.y = fmaxf(fmaxf(mx.y, fmaxf(f0y, f1y)), fmaxf(f2y, f3y));
  }
  for (; i < b1; i += 4){
    unsigned u = h1[(size_t)i * 64 + l];
    float fx = bf16lo(u), fy = bf16hi(u);
    a0.x += fx; a0.y += fy;
    mx.x = fmaxf(mx.x, fx); mx.y = fmaxf(mx.y, fy);
  }
  __shared__ float2 ssum[4][64], smax[4][64];
  ssum[w][l] = { a0.x + a1.x + a2.x + a3.x, a0.y + a1.y + a2.y + a3.y };
  smax[w][l] = mx;
  __syncthreads();
  if (w == 0){
    float2 S = ssum[0][l], M = smax[0][l];
    #pragma unroll
    for (int k = 1; k < 4; ++k){
      S.x += ssum[k][l].x; S.y += ssum[k][l].y;
      M.x = fmaxf(M.x, smax[k][l].x); M.y = fmaxf(M.y, smax[k][l].y);
    }
    atomicAdd(&psum[g * 128 + 2 * l], S.x);
    atomicAdd(&psum[g * 128 + 2 * l + 1], S.y);
    atomicMaxPosF(&pmax[g * 128 + 2 * l], M.x);
    atomicMaxPosF(&pmax[g * 128 + 2 * l + 1], M.y);
  }
}

// post-pool gather via graph->cluster CSR
constexpr int POST_SPLIT = 4;
__launch_bounds__(256)
__global__ void post_pool_g(const unsigned* __restrict__ hp3, const int* __restrict__ gbasep,
                            const int* __restrict__ cidx,
                            float* __restrict__ psum, float* __restrict__ pmax){
  int g = blockIdx.x / POST_SPLIT, sp = blockIdx.x % POST_SPLIT;
  int t = threadIdx.x, w = t >> 6, l = t & 63;
  int s0 = gbasep[g], s1 = gbasep[g + 1];
  int n = s1 - s0;
  int per = (n + POST_SPLIT * 4 - 1) / (POST_SPLIT * 4);
  int b0 = s0 + (sp * 4 + w) * per, b1 = min(b0 + per, s1);
  float2 a0{0.f,0.f}, a1{0.f,0.f}, a2{0.f,0.f}, a3{0.f,0.f};
  float2 mx{0.f,0.f};
  for (int base = b0; base < b1; base += 64){
    int nn = min(64, b1 - base);
    int cid = cidx[base + min(l, nn - 1)];
    int j = 0;
    for (; j + 4 <= nn; j += 4){
      int c0 = __shfl(cid, j);
      int c1 = __shfl(cid, j + 1);
      int c2 = __shfl(cid, j + 2);
      int c3 = __shfl(cid, j + 3);
      unsigned u0 = hp3[(size_t)c0 * 64 + l];
      unsigned u1 = hp3[(size_t)c1 * 64 + l];
      unsigned u2 = hp3[(size_t)c2 * 64 + l];
      unsigned u3 = hp3[(size_t)c3 * 64 + l];
      float f0x = bf16lo(u0), f0y = bf16hi(u0);
      float f1x = bf16lo(u1), f1y = bf16hi(u1);
      float f2x = bf16lo(u2), f2y = bf16hi(u2);
      float f3x = bf16lo(u3), f3y = bf16hi(u3);
      a0.x += f0x; a0.y += f0y; a1.x += f1x; a1.y += f1y;
      a2.x += f2x; a2.y += f2y; a3.x += f3x; a3.y += f3y;
      mx.x = fmaxf(fmaxf(mx.x, fmaxf(f0x, f1x)), fmaxf(f2x, f3x));
      mx.y = fmaxf(fmaxf(mx.y, fmaxf(f0y, f1y)), fmaxf(f2y, f3y));
    }
    for (; j < nn; ++j){
      int c = __shfl(cid, j);
      unsigned u = hp3[(size_t)c * 64 + l];
      float fx = bf16lo(u), fy = bf16hi(u);
      a0.x += fx; a0.y += fy;
      mx.x = fmaxf(mx.x, fx); mx.y = fmaxf(mx.y, fy);
    }
  }
  __shared__ float2 ssum[4][64], smax[4][64];
  ssum[w][l] = { a0.x + a1.x + a2.x + a3.x, a0.y + a1.y + a2.y + a3.y };
  smax[w][l] = mx;
  __syncthreads();
  if (w == 0){
    float2 S = ssum[0][l], M = smax[0][l];
    #pragma unroll
    for (int k = 1; k < 4; ++k){
      S.x += ssum[k][l].x; S.y += ssum[k][l].y;
      M.x = fmaxf(M.x, smax[k][l].x); M.y = fmaxf(M.y, smax[k][l].y);
    }
    atomicAdd(&psum[g * 128 + 2 * l], S.x);
    atomicAdd(&psum[g * 128 + 2 * l + 1], S.y);
    atomicMaxPosF(&pmax[g * 128 + 2 * l], M.x);
    atomicMaxPosF(&pmax[g * 128 + 2 * l + 1], M.y);
  }
}

__launch_bounds__(128)
__global__ void head_kernel(const float* __restrict__ psum, const float* __restrict__ pmax,
                            const float* __restrict__ postsum, const float* __restrict__ postmax,
                            const int* __restrict__ gstart, const int* __restrict__ cntp,
                            const float* __restrict__ l1w, const float* __restrict__ l1b,
                            const float* __restrict__ l2w, const float* __restrict__ l2b,
                            float* __restrict__ out){
  int g = blockIdx.x, t = threadIdx.x;
  __shared__ float z[512];
  __shared__ float a[128];
  __shared__ float logits[16];
  __shared__ float lse_s;
  float cpre  = (float)max(gstart[g + 1] - gstart[g], 1);
  float cpost = fmaxf((float)cntp[g], 1.0f);
  z[t]       = psum[g * 128 + t] / cpre;
  z[128 + t] = pmax[g * 128 + t];
  z[256 + t] = postsum[g * 128 + t] / cpost;
  z[384 + t] = postmax[g * 128 + t];
  __syncthreads();
  float acc = l1b[t];
  #pragma unroll 8
  for (int k = 0; k < 512; ++k) acc = fmaf(z[k], l1w[k * 128 + t], acc);
  a[t] = fmaxf(acc, 0.f);
  __syncthreads();
  if (t < NCLSN){
    float s2 = l2b[t];
    for (int k = 0; k < 128; ++k) s2 = fmaf(a[k], l2w[k * NCLSN + t], s2);
    logits[t] = s2;
  }
  __syncthreads();
  if (t == 0){
    float m = logits[0];
    for (int c = 1; c < NCLSN; ++c) m = fmaxf(m, logits[c]);
    float s = 0.f;
    for (int c = 0; c < NCLSN; ++c) s += expf(logits[c] - m);
    lse_s = m + logf(s);
  }
  __syncthreads();
  if (t < NCLSN) out[g * NCLSN + t] = logits[t] - lse_s;
}

// ---------------------------------------------------------------------------
extern "C" void kernel_launch(void* const* d_in, const int* in_sizes, int n_in,
                              void* d_out, int out_size, void* d_ws, size_t ws_size,
                              hipStream_t stream){
  const float* x       = (const float*)d_in[0];
  const int*   ei      = (const int*)  d_in[1];
  const int*   batch   = (const int*)  d_in[2];
  const int*   cluster = (const int*)  d_in[3];
  const float* W1      = (const float*)d_in[6];
  const float* b1      = (const float*)d_in[7];
  const float* W2      = (const float*)d_in[8];
  const float* b2      = (const float*)d_in[9];
  const float* W3      = (const float*)d_in[10];
  const float* b3      = (const float*)d_in[11];
  const float* l1w     = (const float*)d_in[12];
  const float* l1b     = (const float*)d_in[13];
  const float* l2w     = (const float*)d_in[14];
  const float* l2b     = (const float*)d_in[15];
  float* out = (float*)d_out;

  char* base = (char*)d_ws;
  size_t off = 0;
  auto alloc = [&](size_t bytes) -> char* {
    char* p = base + off;
    off += (bytes + 255) & ~size_t(255);
    return p;
  };
  // ---- zero zone (one memset) ----
  char*  zbase  = base + off;
  int*   cntn   = (int*)  alloc((size_t)N_CLUST * 4);
  int*   deg2   = (int*)  alloc((size_t)N_CLUST * 4);
  int*   cntp   = (int*)  alloc((size_t)N_GRAPH * 4);
  float* pre_s  = (float*)alloc((size_t)N_GRAPH * 128 * 4);
  float* pre_m  = (float*)alloc((size_t)N_GRAPH * 128 * 4);
  float* post_s = (float*)alloc((size_t)N_GRAPH * 128 * 4);
  float* post_m = (float*)alloc((size_t)N_GRAPH * 128 * 4);
  size_t zsize = off;
  // ---- plain buffers (bf16 feature rows: 64 uints per row) ----
  unsigned* Ts1   = (unsigned*)alloc((size_t)N_NODES * 64 * 4);  // later aliased
  unsigned* h1    = (unsigned*)alloc((size_t)N_NODES * 64 * 4);  // stage buf aliases here
  int*   esrc1   = (int*)  alloc((size_t)N_EDGES * 4);
  int*   psrcC   = (int*)  alloc((size_t)N_EDGES * 4);
  int*   deg1    = (int*)  alloc((size_t)N_NODES * 4);
  int*   rowptr1 = (int*)  alloc((size_t)(N_NODES + 1) * 4);
  int*   rowptrn = (int*)  alloc((size_t)(N_CLUST + 1) * 4);
  int*   curn    = (int*)  alloc((size_t)N_CLUST * 4);
  int*   rowptr2 = (int*)  alloc((size_t)(N_CLUST + 1) * 4);
  int*   nidx    = (int*)  alloc((size_t)N_NODES * 4);
  float* dis1    = (float*)alloc((size_t)N_NODES * 4);
  float* dis2    = (float*)alloc((size_t)N_CLUST * 4);
  int*   batchp  = (int*)  alloc((size_t)N_CLUST * 4);
  int*   gstart  = (int*)  alloc((size_t)(N_GRAPH + 1) * 4);
  int*   bsum    = (int*)  alloc((size_t)NBT * 4);
  int*   boff    = (int*)  alloc((size_t)NBT * 4);
  int*   gcnt1   = (int*)  alloc((size_t)NBKT1 * 4);
  int*   gbase1  = (int*)  alloc((size_t)NBKT1 * 4);
  int*   bhist   = (int*)  alloc((size_t)NEB * NBKT1 * 4);
  int*   boffs   = (int*)  alloc((size_t)NEB * NBKT1 * 4);
  int*   gbasep  = (int*)  alloc((size_t)(N_GRAPH + 1) * 4);
  int*   curp    = (int*)  alloc((size_t)N_GRAPH * 4);
  int*   cidx    = (int*)  alloc((size_t)N_CLUST * 4);
  // stage buffer aliases the (not-yet-written) h1 region (6.4 MB <= 25.6 MB)
  unsigned int* stage1 = (unsigned int*)h1;
  // aliases into Ts1 (dead after conv1): 4 x 25000*64 uints = exactly Ts1 size
  unsigned* hp  = Ts1;
  unsigned* Ts2 = Ts1 + (size_t)N_CLUST * 64;
  unsigned* hp2 = Ts1 + (size_t)2 * N_CLUST * 64;
  unsigned* hp3 = Ts1 + (size_t)3 * N_CLUST * 64;
  unsigned* Ts3 = Ts2;

  (void)in_sizes; (void)n_in; (void)out_size; (void)ws_size;

  hipMemsetAsync(zbase, 0, zsize, stream);

  // ---- radix node-CSR build ----
  count_kernel  <<<NEB, 1024, 0, stream>>>(ei, bhist);
  colscan       <<<NBKT1, 512, 0, stream>>>(bhist, boffs, gcnt1);
  bucket_scan   <<<1, 256, 0, stream>>>(gcnt1, gbase1);
  scatter_kernel<<<NEB, 1024, 0, stream>>>(ei, gbase1, boffs, stage1);
  bucket_sort   <<<NBKT1, 1024, 0, stream>>>(stage1, gbase1, gcnt1, esrc1, deg1);
  node_prep<<<(N_NODES + 255) / 256, 256, 0, stream>>>(cluster, deg1, cntn, deg2);
  block_sums <<<NBT, 256, 0, stream>>>(deg1, cntn, deg2, bsum);
  scan_bsums <<<1, 256, 0, stream>>>(bsum, boff, rowptr1, rowptrn, rowptr2);
  scan_final <<<NBT, 256, 0, stream>>>(deg1, cntn, deg2, boff,
                                       rowptr1, dis1, rowptrn, curn, rowptr2, dis2);
  fill_n<<<(N_NODES + 255) / 256, 256, 0, stream>>>(cluster, curn, nidx);
  psrc_build<<<N_CLUST / 4, 256, 0, stream>>>(rowptrn, nidx, rowptr1, esrc1,
                                              cluster, rowptr2, psrcC);

  // conv1 (MFMA one-hot SpMM over node CSR)
  constexpr int NG1 = N_NODES / 16;               // 6250 groups
  constexpr int NG2 = (N_CLUST + 15) / 16;        // 1563 groups
  gemm_mfma<false><<<(N_NODES + 63) / 64, 256, 0, stream>>>(x, W1, dis1, Ts1, N_NODES);
  conv_mfma<<<(NG1 + 3) / 4, 256, 0, stream>>>(Ts1, dis1, rowptr1, esrc1, b1, h1, N_NODES);

  // pre pools (gather over contiguous sorted-batch ranges)
  graph_bounds<<<1, 128, 0, stream>>>(batch, gstart);
  pre_pool_g<<<N_GRAPH * PRE_SPLIT, 256, 0, stream>>>(h1, gstart, pre_s, pre_m);

  // cluster mean pool + batch_p + cntp + graph->cluster CSR
  cluster_gather<<<N_CLUST / 4, 256, 0, stream>>>(h1, rowptrn, nidx, batch, hp, batchp);
  cntp_kernel<<<(N_CLUST + 255) / 256, 256, 0, stream>>>(batchp, cntp);
  scan_cntp<<<1, 64, 0, stream>>>(cntp, gbasep, curp);
  fill_c<<<(N_CLUST + 255) / 256, 256, 0, stream>>>(batchp, curp, cidx);

  // conv2
  gemm_mfma<true><<<(N_CLUST + 63) / 64, 256, 0, stream>>>(hp, W2, dis2, Ts2, N_CLUST);
  conv_mfma<<<(NG2 + 3) / 4, 256, 0, stream>>>(Ts2, dis2, rowptr2, psrcC, b2, hp2, N_CLUST);

  // conv3
  gemm_mfma<true><<<(N_CLUST + 63) / 64, 256, 0, stream>>>(hp2, W3, dis2, Ts3, N_CLUST);
  conv_mfma<<<(NG2 + 3) / 4, 256, 0, stream>>>(Ts3, dis2, rowptr2, psrcC, b3, hp3, N_CLUST);

  // post pools (gather via graph->cluster CSR) + head
  post_pool_g<<<N_GRAPH * POST_SPLIT, 256, 0, stream>>>(hp3, gbasep, cidx, post_s, post_m);
  head_kernel<<<N_GRAPH, 128, 0, stream>>>(pre_s, pre_m, post_s, post_m, gstart, cntp,
                                           l1w, l1b, l2w, l2b, out);
}

// Round 2
// 610.819 us; speedup vs baseline: 1.0288x; 1.0288x over previous
//
#include <hip/hip_runtime.h>

constexpr int N_NODES = 100000;
constexpr int N_EDGES = 1600000;
constexpr int N_CLUST = 25000;
constexpr int N_GRAPH = 64;
constexpr int NCLSN   = 10;

// bucket decomposition for the radix node-CSR build
constexpr int BKT1_SHIFT = 9;                       // node-dst buckets of 512 ids
constexpr int NBKT1 = (N_NODES + 511) / 512;        // 196
constexpr int EPB = 4096;                           // edges per block (count/scatter)
constexpr int NEB = (N_EDGES + EPB - 1) / EPB;      // 391
constexpr int SORT_CAP = 12288;                     // LDS staging cap (mean 8163, sd ~90)

// edge payload layout (esrc1 / psrcC): bits [16:0] = src id, bits [20:17] = dst & 15
// (dst-local row index within a 16-aligned MFMA group; conv_mfma consumes this)
constexpr unsigned PAY_SRC_MASK = 0x1FFFFu;

// scan partitioning: 1024 elements per block, three concatenated segments
constexpr int SCAN_BPB = 1024;
constexpr int NB1 = (N_NODES + SCAN_BPB - 1) / SCAN_BPB;  // 98
constexpr int NB2 = (N_CLUST + SCAN_BPB - 1) / SCAN_BPB;  // 25
constexpr int NB3 = (N_CLUST + SCAN_BPB - 1) / SCAN_BPB;  // 25
constexpr int NBT = NB1 + NB2 + NB3;                      // 148

// ---- bf16 pack/unpack helpers (features stored as packed pairs in uint) ----
__device__ __forceinline__ float bf16lo(unsigned u){ return __uint_as_float(u << 16); }
__device__ __forceinline__ float bf16hi(unsigned u){ return __uint_as_float(u & 0xffff0000u); }
__device__ __forceinline__ unsigned bf16_rne(float f){
  unsigned u = __float_as_uint(f);
  return (u + 0x7fffu + ((u >> 16) & 1u)) >> 16;
}
__device__ __forceinline__ unsigned pack2(float lo, float hi){
  return bf16_rne(lo) | (bf16_rne(hi) << 16);
}

typedef short bf16x8 __attribute__((ext_vector_type(8)));
typedef float f32x4  __attribute__((ext_vector_type(4)));

// ---------------------------------------------------------------------------
// radix node-CSR build, phase 1: per-block bucket histograms (no global atomics)
// ---------------------------------------------------------------------------
__launch_bounds__(1024)
__global__ void count_kernel(const int* __restrict__ ei, int* __restrict__ bhist){
  __shared__ int h1c[NBKT1];
  int t = threadIdx.x;
  for (int i = t; i < NBKT1; i += 1024) h1c[i] = 0;
  __syncthreads();
  int e0 = blockIdx.x * EPB;
  #pragma unroll
  for (int i = 0; i < EPB / 1024; ++i){
    int e = e0 + i * 1024 + t;
    if (e < N_EDGES) atomicAdd(&h1c[ei[N_EDGES + e] >> BKT1_SHIFT], 1);
  }
  __syncthreads();
  for (int i = t; i < NBKT1; i += 1024) bhist[blockIdx.x * NBKT1 + i] = h1c[i];
}

// phase 2a: column scan of the histogram matrix -> per-(block,bucket) offsets
__launch_bounds__(512)
__global__ void colscan(const int* __restrict__ bhist, int* __restrict__ boffs,
                        int* __restrict__ gcnt1){
  __shared__ int s[512];
  int i = blockIdx.x;                 // bucket
  int t = threadIdx.x;                // edge-block index
  int v = (t < NEB) ? bhist[t * NBKT1 + i] : 0;
  s[t] = v; __syncthreads();
  for (int o = 1; o < 512; o <<= 1){
    int a = (t >= o) ? s[t - o] : 0;
    __syncthreads(); s[t] += a; __syncthreads();
  }
  if (t < NEB) boffs[t * NBKT1 + i] = s[t] - v;   // exclusive within column
  if (t == 511) gcnt1[i] = s[511];
}

// phase 2b: bucket bases (prefix over 196 totals)
__launch_bounds__(256)
__global__ void bucket_scan(const int* __restrict__ gcnt1, int* __restrict__ gbase1){
  __shared__ int s[256];
  int t = threadIdx.x;
  int v = (t < NBKT1) ? gcnt1[t] : 0;
  s[t] = v; __syncthreads();
  for (int off = 1; off < 256; off <<= 1){
    int a = (t >= off) ? s[t - off] : 0;
    __syncthreads(); s[t] += a; __syncthreads();
  }
  if (t < NBKT1) gbase1[t] = s[t] - v;
}

// phase 3: single-pass scatter into pre-reserved runs (no global atomics)
__launch_bounds__(1024)
__global__ void scatter_kernel(const int* __restrict__ ei, const int* __restrict__ gbase1,
                               const int* __restrict__ boffs, unsigned int* __restrict__ stage1){
  __shared__ int gb1[NBKT1];
  __shared__ int cur[NBKT1];
  int t = threadIdx.x, b = blockIdx.x;
  for (int i = t; i < NBKT1; i += 1024){
    gb1[i] = gbase1[i] + boffs[b * NBKT1 + i];
    cur[i] = 0;
  }
  __syncthreads();
  int e0 = b * EPB;
  #pragma unroll
  for (int i = 0; i < EPB / 1024; ++i){
    int e = e0 + i * 1024 + t;
    if (e < N_EDGES){
      int src = ei[e], dst = ei[N_EDGES + e];
      int bk = dst >> BKT1_SHIFT;
      int r = atomicAdd(&cur[bk], 1);
      stage1[gb1[bk] + r] = ((unsigned)(dst & 511) << 17) | (unsigned)src;
    }
  }
}

// phase 4: per-bucket LDS counting sort + coalesced degree writes (1024 thr)
// payload keeps bits [20:17] = dst & 15 for the MFMA conv's one-hot build
__launch_bounds__(1024)
__global__ void bucket_sort(const unsigned int* __restrict__ stage, const int* __restrict__ gbase,
                            const int* __restrict__ gcnt, int* __restrict__ outpay,
                            int* __restrict__ deg){
  __shared__ int cnt[512], off[512];
  __shared__ int sorted[SORT_CAP];
  int b = blockIdx.x, t = threadIdx.x;
  int base = gbase[b], n = gcnt[b];
  if (t < 512) cnt[t] = 0;
  __syncthreads();
  for (int i = t; i < n; i += 1024) atomicAdd(&cnt[stage[base + i] >> 17], 1);
  __syncthreads();
  if (t < 512){
    int idx = b * 512 + t;
    if (idx < N_NODES) deg[idx] = cnt[t];
    off[t] = cnt[t];
  }
  __syncthreads();
  for (int s = 1; s < 512; s <<= 1){
    int v = 0;
    if (t < 512 && t >= s) v = off[t - s];
    __syncthreads();
    if (t < 512) off[t] += v;
    __syncthreads();
  }
  if (t < 512) off[t] -= cnt[t];       // exclusive cursors
  __syncthreads();
  if (n <= SORT_CAP){
    for (int i = t; i < n; i += 1024){
      unsigned w = stage[base + i];
      int r = atomicAdd(&off[w >> 17], 1);
      sorted[r] = (int)(w & 0x1FFFFFu);   // src | (dst&15)<<17
    }
    __syncthreads();
    for (int i = t; i < n; i += 1024) outpay[base + i] = sorted[i];
  } else {  // never expected; correct fallback
    for (int i = t; i < n; i += 1024){
      unsigned w = stage[base + i];
      int r = atomicAdd(&off[w >> 17], 1);
      outpay[base + r] = (int)(w & 0x1FFFFFu);
    }
  }
}

// per-node: cluster membership count + cluster in-degree (sum of member deg1)
__global__ void node_prep(const int* __restrict__ cluster, const int* __restrict__ deg1,
                          int* __restrict__ cntn, int* __restrict__ deg2){
  int v = blockIdx.x * blockDim.x + threadIdx.x;
  if (v < N_NODES){
    int c = cluster[v];
    atomicAdd(&cntn[c], 1);
    atomicAdd(&deg2[c], deg1[v]);
  }
}

// ---------------------------------------------------------------------------
// device-wide 3-segment exclusive scan
// ---------------------------------------------------------------------------
__device__ __forceinline__ void seg_select(int b, const int* deg1, const int* cntn,
                                           const int* deg2, const int*& src, int& n, int& base){
  if (b < NB1){ src = deg1; n = N_NODES; base = b * SCAN_BPB; }
  else if (b < NB1 + NB2){ src = cntn; n = N_CLUST; base = (b - NB1) * SCAN_BPB; }
  else { src = deg2; n = N_CLUST; base = (b - NB1 - NB2) * SCAN_BPB; }
}

__launch_bounds__(256)
__global__ void block_sums(const int* __restrict__ deg1, const int* __restrict__ cntn,
                           const int* __restrict__ deg2, int* __restrict__ bsum){
  int b = blockIdx.x;
  const int* src; int n, base;
  seg_select(b, deg1, cntn, deg2, src, n, base);
  int t = threadIdx.x;
  int i0 = base + t * 4;
  int s = 0;
  if (i0 + 3 < n){ int4 v = *(const int4*)&src[i0]; s = v.x + v.y + v.z + v.w; }
  else { for (int j = 0; j < 4; ++j){ int i = i0 + j; if (i < n) s += src[i]; } }
  __shared__ int sh[256];
  sh[t] = s; __syncthreads();
  for (int off = 128; off > 0; off >>= 1){
    if (t < off) sh[t] += sh[t + off];
    __syncthreads();
  }
  if (t == 0) bsum[b] = sh[0];
}

__launch_bounds__(256)
__global__ void scan_bsums(const int* __restrict__ bsum, int* __restrict__ boff,
                           int* __restrict__ rowptr1, int* __restrict__ rowptrn,
                           int* __restrict__ rowptr2){
  __shared__ int s[256];
  int t = threadIdx.x;
  int v = (t < NBT) ? bsum[t] : 0;
  s[t] = v; __syncthreads();
  int seg = (t < NB1) ? 0 : (t < NB1 + NB2 ? 1 : 2);
  for (int off = 1; off < 256; off <<= 1){
    int add = 0;
    if (t >= off){
      int u = t - off;
      int useg = (u < NB1) ? 0 : (u < NB1 + NB2 ? 1 : 2);
      if (useg == seg) add = s[u];
    }
    __syncthreads();
    s[t] += add;
    __syncthreads();
  }
  if (t < NBT) boff[t] = s[t] - v;
  if (t == NB1 - 1)       rowptr1[N_NODES] = s[t];
  if (t == NB1 + NB2 - 1) rowptrn[N_CLUST] = s[t];
  if (t == NBT - 1)       rowptr2[N_CLUST] = s[t];
}

__launch_bounds__(256)
__global__ void scan_final(const int* __restrict__ deg1, const int* __restrict__ cntn,
                           const int* __restrict__ deg2, const int* __restrict__ boff,
                           int* __restrict__ rowptr1, float* __restrict__ dis1,
                           int* __restrict__ rowptrn, int* __restrict__ curn,
                           int* __restrict__ rowptr2, float* __restrict__ dis2){
  int b = blockIdx.x;
  const int* src; int n, base;
  seg_select(b, deg1, cntn, deg2, src, n, base);
  int* rp; int* cur; float* dis;
  if (b < NB1){ rp = rowptr1; cur = nullptr; dis = dis1; }
  else if (b < NB1 + NB2){ rp = rowptrn; cur = curn; dis = nullptr; }
  else { rp = rowptr2; cur = nullptr; dis = dis2; }
  int t = threadIdx.x;
  int i0 = base + t * 4;
  int v[4]; int s = 0;
  #pragma unroll
  for (int j = 0; j < 4; ++j){ int i = i0 + j; v[j] = (i < n) ? src[i] : 0; s += v[j]; }
  __shared__ int sh[256];
  sh[t] = s; __syncthreads();
  for (int off = 1; off < 256; off <<= 1){
    int add = (t >= off) ? sh[t - off] : 0;
    __syncthreads();
    sh[t] += add;
    __syncthreads();
  }
  int run = sh[t] - s + boff[b];
  #pragma unroll
  for (int j = 0; j < 4; ++j){
    int i = i0 + j;
    if (i < n){
      rp[i] = run;
      if (cur) cur[i] = run;
      if (dis) dis[i] = rsqrtf((float)v[j] + 1.0f);
      run += v[j];
    }
  }
}

// node->cluster CSR fill
__global__ void fill_n(const int* __restrict__ cluster, int* __restrict__ curn,
                       int* __restrict__ nidx){
  int v = blockIdx.x * blockDim.x + threadIdx.x;
  if (v >= N_NODES) return;
  nidx[atomicAdd(&curn[cluster[v]], 1)] = v;
}

// ---------------------------------------------------------------------------
// psrcC build: cluster c's pooled-edge list = concat of members' edge runs
// payload: src-cluster | (dst-cluster & 15) << 17
// ---------------------------------------------------------------------------
__launch_bounds__(256)
__global__ void psrc_build(const int* __restrict__ rowptrn, const int* __restrict__ nidx,
                           const int* __restrict__ rowptr1, const int* __restrict__ esrc1,
                           const int* __restrict__ cluster, const int* __restrict__ rowptr2,
                           int* __restrict__ psrcC){
  int c = blockIdx.x * 4 + (threadIdx.x >> 6);
  int l = threadIdx.x & 63;
  int mb = rowptrn[c], me = rowptrn[c + 1];
  int cnt = me - mb;                       // members per cluster (<= 64)
  int base_l = 0, d_l = 0;
  if (l < cnt){
    int v = nidx[mb + l];
    base_l = rowptr1[v];
    d_l = rowptr1[v + 1] - base_l;
  }
  int pref = d_l;                          // inclusive scan over 64 lanes
  #pragma unroll
  for (int off = 1; off < 64; off <<= 1){
    int u = __shfl_up(pref, off);
    if (l >= off) pref += u;
  }
  int total = __shfl(pref, 63);
  int wbase = rowptr2[c];
  int dbits = (c & 15) << 17;
  int iters = (total + 63) >> 6;           // uniform loop; all lanes active
  for (int k = 0; k < iters; ++k){
    int idx = k * 64 + l;
    int idxc = min(idx, total - 1);
    int m = 0;
    for (int j = 0; j < cnt; ++j){
      int pj = __shfl(pref, j);
      if (idxc >= pj) m = j + 1;
    }
    int pm = __shfl(pref, m);
    int dm = __shfl(d_l, m);
    int bm = __shfl(base_l, m);
    int e = bm + idxc - (pm - dm);
    int sc = cluster[esrc1[e] & (int)PAY_SRC_MASK];
    if (idx < total) psrcC[wbase + idx] = sc | dbits;
  }
}

// ---------------------------------------------------------------------------
// MFMA GEMM: C[M,128] = (A[M,128] @ B[128,128]) * scale[row], bf16 packed out
// ---------------------------------------------------------------------------
template<bool A_BF16>
__launch_bounds__(256)
__global__ void gemm_mfma(const void* __restrict__ Aptr, const float* __restrict__ B,
                          const float* __restrict__ scale, unsigned* __restrict__ Cmat,
                          int M){
  __shared__ __align__(16) unsigned Blds[128 * 68];
  __shared__ __align__(16) unsigned Alds[64 * 68];
  const int t = threadIdx.x;
  const int row0 = blockIdx.x * 64;

  #pragma unroll
  for (int i = 0; i < 8; ++i){
    int task = t + i * 256;
    int kp = task >> 5, nq = task & 31;
    float4 b0 = *(const float4*)&B[(2 * kp) * 128 + nq * 4];
    float4 b1 = *(const float4*)&B[(2 * kp + 1) * 128 + nq * 4];
    Blds[(nq * 4 + 0) * 68 + kp] = pack2(b0.x, b1.x);
    Blds[(nq * 4 + 1) * 68 + kp] = pack2(b0.y, b1.y);
    Blds[(nq * 4 + 2) * 68 + kp] = pack2(b0.z, b1.z);
    Blds[(nq * 4 + 3) * 68 + kp] = pack2(b0.w, b1.w);
  }
  if (A_BF16){
    const unsigned* A = (const unsigned*)Aptr;
    #pragma unroll
    for (int i = 0; i < 8; ++i){
      int idx = t + i * 256;
      int row = idx >> 5, c2 = idx & 31;
      int grow = min(row0 + row, M - 1);
      uint2 v = *(const uint2*)&A[(size_t)grow * 64 + c2 * 2];
      Alds[row * 68 + c2 * 2]     = v.x;
      Alds[row * 68 + c2 * 2 + 1] = v.y;
    }
  } else {
    const float* A = (const float*)Aptr;
    #pragma unroll
    for (int i = 0; i < 8; ++i){
      int idx = t + i * 256;
      int row = idx >> 5, k4 = idx & 31;
      int grow = min(row0 + row, M - 1);
      float4 v = *(const float4*)&A[(size_t)grow * 128 + k4 * 4];
      Alds[row * 68 + k4 * 2]     = pack2(v.x, v.y);
      Alds[row * 68 + k4 * 2 + 1] = pack2(v.z, v.w);
    }
  }
  __syncthreads();

  const int wv = t >> 6, l = t & 63, quad = l >> 4, n16 = l & 15;
  f32x4 acc[8];
  #pragma unroll
  for (int nt = 0; nt < 8; ++nt) acc[nt] = (f32x4){0.f, 0.f, 0.f, 0.f};
  const int arow = wv * 16 + n16;
  #pragma unroll
  for (int ks = 0; ks < 4; ++ks){
    bf16x8 af = *(const bf16x8*)&Alds[arow * 68 + ks * 16 + quad * 4];
    #pragma unroll
    for (int nt = 0; nt < 8; ++nt){
      bf16x8 bfr = *(const bf16x8*)&Blds[(nt * 16 + n16) * 68 + ks * 16 + quad * 4];
      acc[nt] = __builtin_amdgcn_mfma_f32_16x16x32_bf16(af, bfr, acc[nt], 0, 0, 0);
    }
  }
  #pragma unroll
  for (int nt = 0; nt < 8; ++nt){
    #pragma unroll
    for (int r = 0; r < 4; ++r){
      int row = row0 + wv * 16 + quad * 4 + r;
      float sc = scale[min(row, M - 1)];
      float v = acc[nt][r] * sc;
      float vhi = __shfl_xor(v, 1);
      if (((l & 1) == 0) && row < M)
        Cmat[(size_t)row * 64 + nt * 8 + (n16 >> 1)] = pack2(v, vhi);
    }
  }
}

// ---------------------------------------------------------------------------
// MFMA CSR conv, software-pipelined: one wave per 16 consecutive dst rows.
// Per 32-edge chunk: gather src rows -> regs (8 batched uint4 loads) ->
// LDS transposed-by-pairs (v_perm), one-hot A[16x32] from payload bits
// [20:17], acc += Onehot . Feat via mfma_f32_16x16x32_bf16.
// Pipeline: while chunk ch runs its LDS+MFMA phase, chunk ch+1's gathers are
// already in flight and chunk ch+2's payload is being fetched. Per-wave DS
// ops execute in order, so the single LDS buffer is hazard-free.
// Self-loop = 16 appended virtual edges (weight 1):
//   out = relu(dis[row] * (sum_e Ts[src] + Ts[row]) + b)
// ---------------------------------------------------------------------------
constexpr int BSTR = 17;   // LDS uints per feature row (odd -> banks spread)

__launch_bounds__(256, 4)
__global__ void conv_mfma(const unsigned* __restrict__ Ts, const float* __restrict__ dis,
                          const int* __restrict__ rowptr, const int* __restrict__ epay,
                          const float* __restrict__ bias, unsigned* __restrict__ Hout,
                          int M){
  __shared__ unsigned Blds[4][128 * BSTR];
  const int t = threadIdx.x, wv = t >> 6, l = t & 63;
  const int gi = blockIdx.x * 4 + wv;
  const int base = gi * 16;
  if (base >= M) return;
  const int n16 = l & 15, quad = l >> 4, k32 = l & 31;
  const int beg = rowptr[base];
  const int end = rowptr[min(base + 16, M)];
  const int cnt = end - beg;
  const int selfN = min(16, M - base);
  const int total = cnt + selfN;
  const int nch = (total + 31) >> 5;
  unsigned* Bl = &Blds[wv][0];

  f32x4 acc[8];
  #pragma unroll
  for (int nt = 0; nt < 8; ++nt) acc[nt] = (f32x4){0.f, 0.f, 0.f, 0.f};
  float bv[8];
  #pragma unroll
  for (int nt = 0; nt < 8; ++nt) bv[nt] = bias[nt * 16 + n16];

  // clamped payload fetch (uniform, non-divergent; OOB lanes decode to self/null)
  auto pay_load = [&](int ch) -> int {
    if (cnt == 0) return 0;
    int ke = min(ch * 32 + k32, cnt - 1);
    return epay[beg + ke];
  };
  auto decode = [&](int ch, int p, int& src, int& d){
    int ke = ch * 32 + k32;
    if (ke < cnt){ src = p & (int)PAY_SRC_MASK; d = (p >> 17) & 15; }
    else {
      int sd = ke - cnt;
      d   = (sd < selfN) ? sd : 31;          // 31 never matches a row -> weight 0
      src = (sd < selfN) ? (base + sd) : 0;  // safe dummy row for OOB lanes
    }
  };
  // batch-issue all 8 gather loads (kept in flight together)
  auto issue = [&](int src, uint4* u){
    int s[8];
    #pragma unroll
    for (int i = 0; i < 4; ++i){
      int pp = quad + i * 4;
      s[2 * i]     = __shfl(src, 2 * pp);
      s[2 * i + 1] = __shfl(src, 2 * pp + 1);
    }
    #pragma unroll
    for (int i = 0; i < 8; ++i)
      u[i] = *(const uint4*)&Ts[(size_t)s[i] * 64 + n16 * 4];
  };
  // stage 32 gathered rows into LDS as [feat][edge-pair] uints
  auto stage = [&](const uint4* u){
    #pragma unroll
    for (int i = 0; i < 4; ++i){
      int pp = quad + i * 4;
      uint4 u0 = u[2 * i], u1 = u[2 * i + 1];
      unsigned* wp = Bl + (n16 * 8) * BSTR + pp;
      wp[0 * BSTR] = __builtin_amdgcn_perm(u1.x, u0.x, 0x05040100u);
      wp[1 * BSTR] = __builtin_amdgcn_perm(u1.x, u0.x, 0x07060302u);
      wp[2 * BSTR] = __builtin_amdgcn_perm(u1.y, u0.y, 0x05040100u);
      wp[3 * BSTR] = __builtin_amdgcn_perm(u1.y, u0.y, 0x07060302u);
      wp[4 * BSTR] = __builtin_amdgcn_perm(u1.z, u0.z, 0x05040100u);
      wp[5 * BSTR] = __builtin_amdgcn_perm(u1.z, u0.z, 0x07060302u);
      wp[6 * BSTR] = __builtin_amdgcn_perm(u1.w, u0.w, 0x05040100u);
      wp[7 * BSTR] = __builtin_amdgcn_perm(u1.w, u0.w, 0x07060302u);
    }
  };
  // one-hot A + B fragments + 8 MFMAs for the chunk staged in LDS
  auto compute = [&](int d){
    union { unsigned u[4]; bf16x8 v; } af;
    #pragma unroll
    for (int jj = 0; jj < 4; ++jj){
      int d0 = __shfl(d, quad * 8 + 2 * jj);
      int d1 = __shfl(d, quad * 8 + 2 * jj + 1);
      af.u[jj] = (d0 == n16 ? 0x3F80u : 0u) | (d1 == n16 ? 0x3F800000u : 0u);
    }
    #pragma unroll
    for (int nt = 0; nt < 8; ++nt){
      union { unsigned u[4]; bf16x8 v; } bf;
      const unsigned* rp = Bl + (nt * 16 + n16) * BSTR + quad * 4;
      bf.u[0] = rp[0]; bf.u[1] = rp[1]; bf.u[2] = rp[2]; bf.u[3] = rp[3];
      acc[nt] = __builtin_amdgcn_mfma_f32_16x16x32_bf16(af.v, bf.v, acc[nt], 0, 0, 0);
    }
  };

  // ---- pipelined main loop ----
  uint4 u[8];
  int p = pay_load(0);
  int src_c, d_c;
  decode(0, p, src_c, d_c);
  issue(src_c, u);                 // chunk 0 gathers in flight
  int p_nxt = pay_load(1);         // chunk 1 payload in flight (clamped-safe)
  for (int ch = 0; ch < nch; ++ch){
    stage(u);                      // waits vmcnt on chunk ch gathers
    int d_keep = d_c;
    if (ch + 1 < nch){
      int s_n, d_n;
      decode(ch + 1, p_nxt, s_n, d_n);
      issue(s_n, u);               // chunk ch+1 gathers in flight under compute
      p_nxt = pay_load(ch + 2);    // chunk ch+2 payload in flight
      d_c = d_n;
    }
    compute(d_keep);               // ds_read + MFMA for chunk ch
  }

  // epilogue: C row = base + quad*4 + r, col = nt*16 + n16
  #pragma unroll
  for (int r = 0; r < 4; ++r){
    int row = base + quad * 4 + r;
    float dsc = dis[min(row, M - 1)];
    #pragma unroll
    for (int nt = 0; nt < 8; ++nt){
      float v = fmaxf(fmaf(dsc, acc[nt][r], bv[nt]), 0.f);
      float vhi = __shfl_xor(v, 1);
      if (((l & 1) == 0) && row < M)
        Hout[(size_t)row * 64 + nt * 8 + (n16 >> 1)] = pack2(v, vhi);
    }
  }
}

// cluster mean pool + batch_p, quarter-wave uint4 gather
__launch_bounds__(256)
__global__ void cluster_gather(const unsigned* __restrict__ h1, const int* __restrict__ rowptrn,
                               const int* __restrict__ nidx, const int* __restrict__ batch,
                               unsigned* __restrict__ hp, int* __restrict__ batchp){
  int c = blockIdx.x * 4 + (threadIdx.x >> 6);
  int l = threadIdx.x & 63;
  int q = l & 15, h = l >> 4;
  int mb = rowptrn[c], me = rowptrn[c + 1];
  float acc[8] = {0.f,0.f,0.f,0.f,0.f,0.f,0.f,0.f};
  int vmax = -1;
  for (int base = mb; base < me; base += 64){
    int n = min(64, me - base);
    int vid = nidx[base + min(l, n - 1)];
    if (l < n) vmax = max(vmax, vid);
    int j = 0;
    for (; j + 8 <= n; j += 8){
      int s0 = __shfl(vid, j + h);
      int s1 = __shfl(vid, j + 4 + h);
      uint4 u0 = *(const uint4*)&h1[(size_t)s0 * 64 + q * 4];
      uint4 u1 = *(const uint4*)&h1[(size_t)s1 * 64 + q * 4];
      acc[0] += bf16lo(u0.x); acc[1] += bf16hi(u0.x);
      acc[2] += bf16lo(u0.y); acc[3] += bf16hi(u0.y);
      acc[4] += bf16lo(u0.z); acc[5] += bf16hi(u0.z);
      acc[6] += bf16lo(u0.w); acc[7] += bf16hi(u0.w);
      acc[0] += bf16lo(u1.x); acc[1] += bf16hi(u1.x);
      acc[2] += bf16lo(u1.y); acc[3] += bf16hi(u1.y);
      acc[4] += bf16lo(u1.z); acc[5] += bf16hi(u1.z);
      acc[6] += bf16lo(u1.w); acc[7] += bf16hi(u1.w);
    }
    for (; j < n; j += 4){
      int ei = j + h;
      int s = __shfl(vid, min(ei, n - 1));
      uint4 u = *(const uint4*)&h1[(size_t)s * 64 + q * 4];
      if (ei < n){
        acc[0] += bf16lo(u.x); acc[1] += bf16hi(u.x);
        acc[2] += bf16lo(u.y); acc[3] += bf16hi(u.y);
        acc[4] += bf16lo(u.z); acc[5] += bf16hi(u.z);
        acc[6] += bf16lo(u.w); acc[7] += bf16hi(u.w);
      }
    }
  }
  #pragma unroll
  for (int k = 0; k < 8; ++k){
    acc[k] += __shfl_xor(acc[k], 16);
    acc[k] += __shfl_xor(acc[k], 32);
  }
  #pragma unroll
  for (int off = 32; off > 0; off >>= 1) vmax = max(vmax, __shfl_xor(vmax, off));
  float inv = 1.0f / (float)max(me - mb, 1);
  if (h == 0){
    uint4 o;
    o.x = pack2(acc[0] * inv, acc[1] * inv);
    o.y = pack2(acc[2] * inv, acc[3] * inv);
    o.z = pack2(acc[4] * inv, acc[5] * inv);
    o.w = pack2(acc[6] * inv, acc[7] * inv);
    *(uint4*)&hp[(size_t)c * 64 + q * 4] = o;
  }
  if (l == 0) batchp[c] = (vmax >= 0) ? batch[vmax] : 0;  // batch sorted by node id
}

__global__ void cntp_kernel(const int* __restrict__ batchp, int* __restrict__ cntp){
  int c = blockIdx.x * blockDim.x + threadIdx.x;
  if (c < N_CLUST) atomicAdd(&cntp[batchp[c]], 1);
}

// graph -> cluster CSR: scan cntp (64 entries) + cursor fill
__global__ void scan_cntp(const int* __restrict__ cntp, int* __restrict__ gbasep,
                          int* __restrict__ curp){
  int t = threadIdx.x;                 // 64 threads
  int v = cntp[t];
  int s = v;
  for (int off = 1; off < 64; off <<= 1){
    int u = __shfl_up(s, off);
    if (t >= off) s += u;
  }
  gbasep[t] = s - v; curp[t] = s - v;
  if (t == 63) gbasep[64] = s;
}

__global__ void fill_c(const int* __restrict__ batchp, int* __restrict__ curp,
                       int* __restrict__ cidx){
  int c = blockIdx.x * blockDim.x + threadIdx.x;
  if (c < N_CLUST) cidx[atomicAdd(&curp[batchp[c]], 1)] = c;
}

// ---------------------------------------------------------------------------
__global__ void graph_bounds(const int* __restrict__ batch, int* __restrict__ gstart){
  int g = threadIdx.x;
  if (g > N_GRAPH) return;
  int lo = 0, hi = N_NODES;
  while (lo < hi){ int mid = (lo + hi) >> 1; if (batch[mid] < g) lo = mid + 1; else hi = mid; }
  gstart[g] = lo;
}

__device__ __forceinline__ void atomicMaxPosF(float* addr, float v){
  atomicMax((int*)addr, __float_as_int(v));
}

// pre-pool gather: graph g's rows are contiguous [gstart[g], gstart[g+1])
constexpr int PRE_SPLIT = 8;
__launch_bounds__(256)
__global__ void pre_pool_g(const unsigned* __restrict__ h1, const int* __restrict__ gstart,
                           float* __restrict__ psum, float* __restrict__ pmax){
  int g = blockIdx.x / PRE_SPLIT, sp = blockIdx.x % PRE_SPLIT;
  int t = threadIdx.x, w = t >> 6, l = t & 63;
  int s0 = gstart[g], s1 = gstart[g + 1];
  int n = s1 - s0;
  int per = (n + PRE_SPLIT - 1) / PRE_SPLIT;
  int b0 = s0 + sp * per, b1 = min(b0 + per, s1);
  float2 a0{0.f,0.f}, a1{0.f,0.f}, a2{0.f,0.f}, a3{0.f,0.f};
  float2 mx{0.f,0.f};
  int i = b0 + w;
  for (; i + 12 < b1; i += 16){
    unsigned u0 = h1[(size_t)(i     ) * 64 + l];
    unsigned u1 = h1[(size_t)(i +  4) * 64 + l];
    unsigned u2 = h1[(size_t)(i +  8) * 64 + l];
    unsigned u3 = h1[(size_t)(i + 12) * 64 + l];
    float f0x = bf16lo(u0), f0y = bf16hi(u0);
    float f1x = bf16lo(u1), f1y = bf16hi(u1);
    float f2x = bf16lo(u2), f2y = bf16hi(u2);
    float f3x = bf16lo(u3), f3y = bf16hi(u3);
    a0.x += f0x; a0.y += f0y; a1.x += f1x; a1.y += f1y;
    a2.x += f2x; a2.y += f2y; a3.x += f3x; a3.y += f3y;
    mx.x = fmaxf(fmaxf(mx.x, fmaxf(f0x, f1x)), fmaxf(f2x, f3x));
    mx.y = fmaxf(fmaxf(mx.y, fmaxf(f0y, f1y)), fmaxf(f2y, f3y));
  }
  for (; i < b1; i += 4){
    unsigned u = h1[(size_t)i * 64 + l];
    float fx = bf16lo(u), fy = bf16hi(u);
    a0.x += fx; a0.y += fy;
    mx.x = fmaxf(mx.x, fx); mx.y = fmaxf(mx.y, fy);
  }
  __shared__ float2 ssum[4][64], smax[4][64];
  ssum[w][l] = { a0.x + a1.x + a2.x + a3.x, a0.y + a1.y + a2.y + a3.y };
  smax[w][l] = mx;
  __syncthreads();
  if (w == 0){
    float2 S = ssum[0][l], M = smax[0][l];
    #pragma unroll
    for (int k = 1; k < 4; ++k){
      S.x += ssum[k][l].x; S.y += ssum[k][l].y;
      M.x = fmaxf(M.x, smax[k][l].x); M.y = fmaxf(M.y, smax[k][l].y);
    }
    atomicAdd(&psum[g * 128 + 2 * l], S.x);
    atomicAdd(&psum[g * 128 + 2 * l + 1], S.y);
    atomicMaxPosF(&pmax[g * 128 + 2 * l], M.x);
    atomicMaxPosF(&pmax[g * 128 + 2 * l + 1], M.y);
  }
}

// post-pool gather via graph->cluster CSR
constexpr int POST_SPLIT = 4;
__launch_bounds__(256)
__global__ void post_pool_g(const unsigned* __restrict__ hp3, const int* __restrict__ gbasep,
                            const int* __restrict__ cidx,
                            float* __restrict__ psum, float* __restrict__ pmax){
  int g = blockIdx.x / POST_SPLIT, sp = blockIdx.x % POST_SPLIT;
  int t = threadIdx.x, w = t >> 6, l = t & 63;
  int s0 = gbasep[g], s1 = gbasep[g + 1];
  int n = s1 - s0;
  int per = (n + POST_SPLIT * 4 - 1) / (POST_SPLIT * 4);
  int b0 = s0 + (sp * 4 + w) * per, b1 = min(b0 + per, s1);
  float2 a0{0.f,0.f}, a1{0.f,0.f}, a2{0.f,0.f}, a3{0.f,0.f};
  float2 mx{0.f,0.f};
  for (int base = b0; base < b1; base += 64){
    int nn = min(64, b1 - base);
    int cid = cidx[base + min(l, nn - 1)];
    int j = 0;
    for (; j + 4 <= nn; j += 4){
      int c0 = __shfl(cid, j);
      int c1 = __shfl(cid, j + 1);
      int c2 = __shfl(cid, j + 2);
      int c3 = __shfl(cid, j + 3);
      unsigned u0 = hp3[(size_t)c0 * 64 + l];
      unsigned u1 = hp3[(size_t)c1 * 64 + l];
      unsigned u2 = hp3[(size_t)c2 * 64 + l];
      unsigned u3 = hp3[(size_t)c3 * 64 + l];
      float f0x = bf16lo(u0), f0y = bf16hi(u0);
      float f1x = bf16lo(u1), f1y = bf16hi(u1);
      float f2x = bf16lo(u2), f2y = bf16hi(u2);
      float f3x = bf16lo(u3), f3y = bf16hi(u3);
      a0.x += f0x; a0.y += f0y; a1.x += f1x; a1.y += f1y;
      a2.x += f2x; a2.y += f2y; a3.x += f3x; a3.y += f3y;
      mx.x = fmaxf(fmaxf(mx.x, fmaxf(f0x, f1x)), fmaxf(f2x, f3x));
      mx.y = fmaxf(fmaxf(mx.y, fmaxf(f0y, f1y)), fmaxf(f2y, f3y));
    }
    for (; j < nn; ++j){
      int c = __shfl(cid, j);
      unsigned u = hp3[(size_t)c * 64 + l];
      float fx = bf16lo(u), fy = bf16hi(u);
      a0.x += fx; a0.y += fy;
      mx.x = fmaxf(mx.x, fx); mx.y = fmaxf(mx.y, fy);
    }
  }
  __shared__ float2 ssum[4][64], smax[4][64];
  ssum[w][l] = { a0.x + a1.x + a2.x + a3.x, a0.y + a1.y + a2.y + a3.y };
  smax[w][l] = mx;
  __syncthreads();
  if (w == 0){
    float2 S = ssum[0][l], M = smax[0][l];
    #pragma unroll
    for (int k = 1; k < 4; ++k){
      S.x += ssum[k][l].x; S.y += ssum[k][l].y;
      M.x = fmaxf(M.x, smax[k][l].x); M.y = fmaxf(M.y, smax[k][l].y);
    }
    atomicAdd(&psum[g * 128 + 2 * l], S.x);
    atomicAdd(&psum[g * 128 + 2 * l + 1], S.y);
    atomicMaxPosF(&pmax[g * 128 + 2 * l], M.x);
    atomicMaxPosF(&pmax[g * 128 + 2 * l + 1], M.y);
  }
}

__launch_bounds__(128)
__global__ void head_kernel(const float* __restrict__ psum, const float* __restrict__ pmax,
                            const float* __restrict__ postsum, const float* __restrict__ postmax,
                            const int* __restrict__ gstart, const int* __restrict__ cntp,
                            const float* __restrict__ l1w, const float* __restrict__ l1b,
                            const float* __restrict__ l2w, const float* __restrict__ l2b,
                            float* __restrict__ out){
  int g = blockIdx.x, t = threadIdx.x;
  __shared__ float z[512];
  __shared__ float a[128];
  __shared__ float logits[16];
  __shared__ float lse_s;
  float cpre  = (float)max(gstart[g + 1] - gstart[g], 1);
  float cpost = fmaxf((float)cntp[g], 1.0f);
  z[t]       = psum[g * 128 + t] / cpre;
  z[128 + t] = pmax[g * 128 + t];
  z[256 + t] = postsum[g * 128 + t] / cpost;
  z[384 + t] = postmax[g * 128 + t];
  __syncthreads();
  float acc = l1b[t];
  #pragma unroll 8
  for (int k = 0; k < 512; ++k) acc = fmaf(z[k], l1w[k * 128 + t], acc);
  a[t] = fmaxf(acc, 0.f);
  __syncthreads();
  if (t < NCLSN){
    float s2 = l2b[t];
    for (int k = 0; k < 128; ++k) s2 = fmaf(a[k], l2w[k * NCLSN + t], s2);
    logits[t] = s2;
  }
  __syncthreads();
  if (t == 0){
    float m = logits[0];
    for (int c = 1; c < NCLSN; ++c) m = fmaxf(m, logits[c]);
    float s = 0.f;
    for (int c = 0; c < NCLSN; ++c) s += expf(logits[c] - m);
    lse_s = m + logf(s);
  }
  __syncthreads();
  if (t < NCLSN) out[g * NCLSN + t] = logits[t] - lse_s;
}

// ---------------------------------------------------------------------------
extern "C" void kernel_launch(void* const* d_in, const int* in_sizes, int n_in,
                              void* d_out, int out_size, void* d_ws, size_t ws_size,
                              hipStream_t stream){
  const float* x       = (const float*)d_in[0];
  const int*   ei      = (const int*)  d_in[1];
  const int*   batch   = (const int*)  d_in[2];
  const int*   cluster = (const int*)  d_in[3];
  const float* W1      = (const float*)d_in[6];
  const float* b1      = (const float*)d_in[7];
  const float* W2      = (const float*)d_in[8];
  const float* b2      = (const float*)d_in[9];
  const float* W3      = (const float*)d_in[10];
  const float* b3      = (const float*)d_in[11];
  const float* l1w     = (const float*)d_in[12];
  const float* l1b     = (const float*)d_in[13];
  const float* l2w     = (const float*)d_in[14];
  const float* l2b     = (const float*)d_in[15];
  float* out = (float*)d_out;

  char* base = (char*)d_ws;
  size_t off = 0;
  auto alloc = [&](size_t bytes) -> char* {
    char* p = base + off;
    off += (bytes + 255) & ~size_t(255);
    return p;
  };
  // ---- zero zone (one memset) ----
  char*  zbase  = base + off;
  int*   cntn   = (int*)  alloc((size_t)N_CLUST * 4);
  int*   deg2   = (int*)  alloc((size_t)N_CLUST * 4);
  int*   cntp   = (int*)  alloc((size_t)N_GRAPH * 4);
  float* pre_s  = (float*)alloc((size_t)N_GRAPH * 128 * 4);
  float* pre_m  = (float*)alloc((size_t)N_GRAPH * 128 * 4);
  float* post_s = (float*)alloc((size_t)N_GRAPH * 128 * 4);
  float* post_m = (float*)alloc((size_t)N_GRAPH * 128 * 4);
  size_t zsize = off;
  // ---- plain buffers (bf16 feature rows: 64 uints per row) ----
  unsigned* Ts1   = (unsigned*)alloc((size_t)N_NODES * 64 * 4);  // later aliased
  unsigned* h1    = (unsigned*)alloc((size_t)N_NODES * 64 * 4);  // stage buf aliases here
  int*   esrc1   = (int*)  alloc((size_t)N_EDGES * 4);
  int*   psrcC   = (int*)  alloc((size_t)N_EDGES * 4);
  int*   deg1    = (int*)  alloc((size_t)N_NODES * 4);
  int*   rowptr1 = (int*)  alloc((size_t)(N_NODES + 1) * 4);
  int*   rowptrn = (int*)  alloc((size_t)(N_CLUST + 1) * 4);
  int*   curn    = (int*)  alloc((size_t)N_CLUST * 4);
  int*   rowptr2 = (int*)  alloc((size_t)(N_CLUST + 1) * 4);
  int*   nidx    = (int*)  alloc((size_t)N_NODES * 4);
  float* dis1    = (float*)alloc((size_t)N_NODES * 4);
  float* dis2    = (float*)alloc((size_t)N_CLUST * 4);
  int*   batchp  = (int*)  alloc((size_t)N_CLUST * 4);
  int*   gstart  = (int*)  alloc((size_t)(N_GRAPH + 1) * 4);
  int*   bsum    = (int*)  alloc((size_t)NBT * 4);
  int*   boff    = (int*)  alloc((size_t)NBT * 4);
  int*   gcnt1   = (int*)  alloc((size_t)NBKT1 * 4);
  int*   gbase1  = (int*)  alloc((size_t)NBKT1 * 4);
  int*   bhist   = (int*)  alloc((size_t)NEB * NBKT1 * 4);
  int*   boffs   = (int*)  alloc((size_t)NEB * NBKT1 * 4);
  int*   gbasep  = (int*)  alloc((size_t)(N_GRAPH + 1) * 4);
  int*   curp    = (int*)  alloc((size_t)N_GRAPH * 4);
  int*   cidx    = (int*)  alloc((size_t)N_CLUST * 4);
  // stage buffer aliases the (not-yet-written) h1 region (6.4 MB <= 25.6 MB)
  unsigned int* stage1 = (unsigned int*)h1;
  // aliases into Ts1 (dead after conv1): 4 x 25000*64 uints = exactly Ts1 size
  unsigned* hp  = Ts1;
  unsigned* Ts2 = Ts1 + (size_t)N_CLUST * 64;
  unsigned* hp2 = Ts1 + (size_t)2 * N_CLUST * 64;
  unsigned* hp3 = Ts1 + (size_t)3 * N_CLUST * 64;
  unsigned* Ts3 = Ts2;

  (void)in_sizes; (void)n_in; (void)out_size; (void)ws_size;

  hipMemsetAsync(zbase, 0, zsize, stream);

  // ---- radix node-CSR build ----
  count_kernel  <<<NEB, 1024, 0, stream>>>(ei, bhist);
  colscan       <<<NBKT1, 512, 0, stream>>>(bhist, boffs, gcnt1);
  bucket_scan   <<<1, 256, 0, stream>>>(gcnt1, gbase1);
  scatter_kernel<<<NEB, 1024, 0, stream>>>(ei, gbase1, boffs, stage1);
  bucket_sort   <<<NBKT1, 1024, 0, stream>>>(stage1, gbase1, gcnt1, esrc1, deg1);
  node_prep<<<(N_NODES + 255) / 256, 256, 0, stream>>>(cluster, deg1, cntn, deg2);
  block_sums <<<NBT, 256, 0, stream>>>(deg1, cntn, deg2, bsum);
  scan_bsums <<<1, 256, 0, stream>>>(bsum, boff, rowptr1, rowptrn, rowptr2);
  scan_final <<<NBT, 256, 0, stream>>>(deg1, cntn, deg2, boff,
                                       rowptr1, dis1, rowptrn, curn, rowptr2, dis2);
  fill_n<<<(N_NODES + 255) / 256, 256, 0, stream>>>(cluster, curn, nidx);
  psrc_build<<<N_CLUST / 4, 256, 0, stream>>>(rowptrn, nidx, rowptr1, esrc1,
                                              cluster, rowptr2, psrcC);

  // conv1 (MFMA one-hot SpMM over node CSR)
  constexpr int NG1 = N_NODES / 16;               // 6250 groups
  constexpr int NG2 = (N_CLUST + 15) / 16;        // 1563 groups
  gemm_mfma<false><<<(N_NODES + 63) / 64, 256, 0, stream>>>(x, W1, dis1, Ts1, N_NODES);
  conv_mfma<<<(NG1 + 3) / 4, 256, 0, stream>>>(Ts1, dis1, rowptr1, esrc1, b1, h1, N_NODES);

  // pre pools (gather over contiguous sorted-batch ranges)
  graph_bounds<<<1, 128, 0, stream>>>(batch, gstart);
  pre_pool_g<<<N_GRAPH * PRE_SPLIT, 256, 0, stream>>>(h1, gstart, pre_s, pre_m);

  // cluster mean pool + batch_p + cntp + graph->cluster CSR
  cluster_gather<<<N_CLUST / 4, 256, 0, stream>>>(h1, rowptrn, nidx, batch, hp, batchp);
  cntp_kernel<<<(N_CLUST + 255) / 256, 256, 0, stream>>>(batchp, cntp);
  scan_cntp<<<1, 64, 0, stream>>>(cntp, gbasep, curp);
  fill_c<<<(N_CLUST + 255) / 256, 256, 0, stream>>>(batchp, curp, cidx);

  // conv2
  gemm_mfma<true><<<(N_CLUST + 63) / 64, 256, 0, stream>>>(hp, W2, dis2, Ts2, N_CLUST);
  conv_mfma<<<(NG2 + 3) / 4, 256, 0, stream>>>(Ts2, dis2, rowptr2, psrcC, b2, hp2, N_CLUST);

  // conv3
  gemm_mfma<true><<<(N_CLUST + 63) / 64, 256, 0, stream>>>(hp2, W3, dis2, Ts3, N_CLUST);
  conv_mfma<<<(NG2 + 3) / 4, 256, 0, stream>>>(Ts3, dis2, rowptr2, psrcC, b3, hp3, N_CLUST);

  // post pools (gather via graph->cluster CSR) + head
  post_pool_g<<<N_GRAPH * POST_SPLIT, 256, 0, stream>>>(hp3, gbasep, cidx, post_s, post_m);
  head_kernel<<<N_GRAPH, 128, 0, stream>>>(pre_s, pre_m, post_s, post_m, gstart, cntp,
                                           l1w, l1b, l2w, l2b, out);
}

// Round 3
// 586.483 us; speedup vs baseline: 1.0715x; 1.0415x over previous
//
#include <hip/hip_runtime.h>

constexpr int N_NODES = 100000;
constexpr int N_EDGES = 1600000;
constexpr int N_CLUST = 25000;
constexpr int N_GRAPH = 64;
constexpr int NCLSN   = 10;

// bucket decomposition for the radix node-CSR build
constexpr int BKT1_SHIFT = 9;                       // node-dst buckets of 512 ids
constexpr int NBKT1 = (N_NODES + 511) / 512;        // 196
constexpr int EPB = 4096;                           // edges per block (count/scatter)
constexpr int NEB = (N_EDGES + EPB - 1) / EPB;      // 391
constexpr int SORT_CAP = 12288;                     // LDS staging cap (mean 8163, sd ~90)

// edge payload layout (esrc1 / psrcC): bits [16:0] = src id, bits [20:17] = dst & 15
// (dst-local row index within a 16-aligned MFMA group; conv_mfma consumes this)
constexpr unsigned PAY_SRC_MASK = 0x1FFFFu;

// scan partitioning: 1024 elements per block, three concatenated segments
constexpr int SCAN_BPB = 1024;
constexpr int NB1 = (N_NODES + SCAN_BPB - 1) / SCAN_BPB;  // 98
constexpr int NB2 = (N_CLUST + SCAN_BPB - 1) / SCAN_BPB;  // 25
constexpr int NB3 = (N_CLUST + SCAN_BPB - 1) / SCAN_BPB;  // 25
constexpr int NBT = NB1 + NB2 + NB3;                      // 148

// ---- bf16 pack/unpack helpers (features stored as packed pairs in uint) ----
__device__ __forceinline__ float bf16lo(unsigned u){ return __uint_as_float(u << 16); }
__device__ __forceinline__ float bf16hi(unsigned u){ return __uint_as_float(u & 0xffff0000u); }
__device__ __forceinline__ unsigned bf16_rne(float f){
  unsigned u = __float_as_uint(f);
  return (u + 0x7fffu + ((u >> 16) & 1u)) >> 16;
}
__device__ __forceinline__ unsigned pack2(float lo, float hi){
  return bf16_rne(lo) | (bf16_rne(hi) << 16);
}

typedef short bf16x8 __attribute__((ext_vector_type(8)));
typedef float f32x4  __attribute__((ext_vector_type(4)));

// ---------------------------------------------------------------------------
// radix node-CSR build, phase 1: per-block bucket histograms (no global atomics)
// ---------------------------------------------------------------------------
__launch_bounds__(1024)
__global__ void count_kernel(const int* __restrict__ ei, int* __restrict__ bhist){
  __shared__ int h1c[NBKT1];
  int t = threadIdx.x;
  for (int i = t; i < NBKT1; i += 1024) h1c[i] = 0;
  __syncthreads();
  int e0 = blockIdx.x * EPB;
  #pragma unroll
  for (int i = 0; i < EPB / 1024; ++i){
    int e = e0 + i * 1024 + t;
    if (e < N_EDGES) atomicAdd(&h1c[ei[N_EDGES + e] >> BKT1_SHIFT], 1);
  }
  __syncthreads();
  for (int i = t; i < NBKT1; i += 1024) bhist[blockIdx.x * NBKT1 + i] = h1c[i];
}

// phase 2a: column scan of the histogram matrix -> per-(block,bucket) offsets
__launch_bounds__(512)
__global__ void colscan(const int* __restrict__ bhist, int* __restrict__ boffs,
                        int* __restrict__ gcnt1){
  __shared__ int s[512];
  int i = blockIdx.x;                 // bucket
  int t = threadIdx.x;                // edge-block index
  int v = (t < NEB) ? bhist[t * NBKT1 + i] : 0;
  s[t] = v; __syncthreads();
  for (int o = 1; o < 512; o <<= 1){
    int a = (t >= o) ? s[t - o] : 0;
    __syncthreads(); s[t] += a; __syncthreads();
  }
  if (t < NEB) boffs[t * NBKT1 + i] = s[t] - v;   // exclusive within column
  if (t == 511) gcnt1[i] = s[511];
}

// phase 2b: bucket bases (prefix over 196 totals)
__launch_bounds__(256)
__global__ void bucket_scan(const int* __restrict__ gcnt1, int* __restrict__ gbase1){
  __shared__ int s[256];
  int t = threadIdx.x;
  int v = (t < NBKT1) ? gcnt1[t] : 0;
  s[t] = v; __syncthreads();
  for (int off = 1; off < 256; off <<= 1){
    int a = (t >= off) ? s[t - off] : 0;
    __syncthreads(); s[t] += a; __syncthreads();
  }
  if (t < NBKT1) gbase1[t] = s[t] - v;
}

// phase 3: single-pass scatter into pre-reserved runs (no global atomics)
__launch_bounds__(1024)
__global__ void scatter_kernel(const int* __restrict__ ei, const int* __restrict__ gbase1,
                               const int* __restrict__ boffs, unsigned int* __restrict__ stage1){
  __shared__ int gb1[NBKT1];
  __shared__ int cur[NBKT1];
  int t = threadIdx.x, b = blockIdx.x;
  for (int i = t; i < NBKT1; i += 1024){
    gb1[i] = gbase1[i] + boffs[b * NBKT1 + i];
    cur[i] = 0;
  }
  __syncthreads();
  int e0 = b * EPB;
  #pragma unroll
  for (int i = 0; i < EPB / 1024; ++i){
    int e = e0 + i * 1024 + t;
    if (e < N_EDGES){
      int src = ei[e], dst = ei[N_EDGES + e];
      int bk = dst >> BKT1_SHIFT;
      int r = atomicAdd(&cur[bk], 1);
      stage1[gb1[bk] + r] = ((unsigned)(dst & 511) << 17) | (unsigned)src;
    }
  }
}

// phase 4: per-bucket LDS counting sort + coalesced degree writes (1024 thr)
// payload keeps bits [20:17] = dst & 15 for the MFMA conv's one-hot build
__launch_bounds__(1024)
__global__ void bucket_sort(const unsigned int* __restrict__ stage, const int* __restrict__ gbase,
                            const int* __restrict__ gcnt, int* __restrict__ outpay,
                            int* __restrict__ deg){
  __shared__ int cnt[512], off[512];
  __shared__ int sorted[SORT_CAP];
  int b = blockIdx.x, t = threadIdx.x;
  int base = gbase[b], n = gcnt[b];
  if (t < 512) cnt[t] = 0;
  __syncthreads();
  for (int i = t; i < n; i += 1024) atomicAdd(&cnt[stage[base + i] >> 17], 1);
  __syncthreads();
  if (t < 512){
    int idx = b * 512 + t;
    if (idx < N_NODES) deg[idx] = cnt[t];
    off[t] = cnt[t];
  }
  __syncthreads();
  for (int s = 1; s < 512; s <<= 1){
    int v = 0;
    if (t < 512 && t >= s) v = off[t - s];
    __syncthreads();
    if (t < 512) off[t] += v;
    __syncthreads();
  }
  if (t < 512) off[t] -= cnt[t];       // exclusive cursors
  __syncthreads();
  if (n <= SORT_CAP){
    for (int i = t; i < n; i += 1024){
      unsigned w = stage[base + i];
      int r = atomicAdd(&off[w >> 17], 1);
      sorted[r] = (int)(w & 0x1FFFFFu);   // src | (dst&15)<<17
    }
    __syncthreads();
    for (int i = t; i < n; i += 1024) outpay[base + i] = sorted[i];
  } else {  // never expected; correct fallback
    for (int i = t; i < n; i += 1024){
      unsigned w = stage[base + i];
      int r = atomicAdd(&off[w >> 17], 1);
      outpay[base + r] = (int)(w & 0x1FFFFFu);
    }
  }
}

// per-node: cluster membership count + cluster in-degree (sum of member deg1)
__global__ void node_prep(const int* __restrict__ cluster, const int* __restrict__ deg1,
                          int* __restrict__ cntn, int* __restrict__ deg2){
  int v = blockIdx.x * blockDim.x + threadIdx.x;
  if (v < N_NODES){
    int c = cluster[v];
    atomicAdd(&cntn[c], 1);
    atomicAdd(&deg2[c], deg1[v]);
  }
}

// ---------------------------------------------------------------------------
// device-wide 3-segment exclusive scan
// ---------------------------------------------------------------------------
__device__ __forceinline__ void seg_select(int b, const int* deg1, const int* cntn,
                                           const int* deg2, const int*& src, int& n, int& base){
  if (b < NB1){ src = deg1; n = N_NODES; base = b * SCAN_BPB; }
  else if (b < NB1 + NB2){ src = cntn; n = N_CLUST; base = (b - NB1) * SCAN_BPB; }
  else { src = deg2; n = N_CLUST; base = (b - NB1 - NB2) * SCAN_BPB; }
}

__launch_bounds__(256)
__global__ void block_sums(const int* __restrict__ deg1, const int* __restrict__ cntn,
                           const int* __restrict__ deg2, int* __restrict__ bsum){
  int b = blockIdx.x;
  const int* src; int n, base;
  seg_select(b, deg1, cntn, deg2, src, n, base);
  int t = threadIdx.x;
  int i0 = base + t * 4;
  int s = 0;
  if (i0 + 3 < n){ int4 v = *(const int4*)&src[i0]; s = v.x + v.y + v.z + v.w; }
  else { for (int j = 0; j < 4; ++j){ int i = i0 + j; if (i < n) s += src[i]; } }
  __shared__ int sh[256];
  sh[t] = s; __syncthreads();
  for (int off = 128; off > 0; off >>= 1){
    if (t < off) sh[t] += sh[t + off];
    __syncthreads();
  }
  if (t == 0) bsum[b] = sh[0];
}

__launch_bounds__(256)
__global__ void scan_bsums(const int* __restrict__ bsum, int* __restrict__ boff,
                           int* __restrict__ rowptr1, int* __restrict__ rowptrn,
                           int* __restrict__ rowptr2){
  __shared__ int s[256];
  int t = threadIdx.x;
  int v = (t < NBT) ? bsum[t] : 0;
  s[t] = v; __syncthreads();
  int seg = (t < NB1) ? 0 : (t < NB1 + NB2 ? 1 : 2);
  for (int off = 1; off < 256; off <<= 1){
    int add = 0;
    if (t >= off){
      int u = t - off;
      int useg = (u < NB1) ? 0 : (u < NB1 + NB2 ? 1 : 2);
      if (useg == seg) add = s[u];
    }
    __syncthreads();
    s[t] += add;
    __syncthreads();
  }
  if (t < NBT) boff[t] = s[t] - v;
  if (t == NB1 - 1)       rowptr1[N_NODES] = s[t];
  if (t == NB1 + NB2 - 1) rowptrn[N_CLUST] = s[t];
  if (t == NBT - 1)       rowptr2[N_CLUST] = s[t];
}

__launch_bounds__(256)
__global__ void scan_final(const int* __restrict__ deg1, const int* __restrict__ cntn,
                           const int* __restrict__ deg2, const int* __restrict__ boff,
                           int* __restrict__ rowptr1, float* __restrict__ dis1,
                           int* __restrict__ rowptrn, int* __restrict__ curn,
                           int* __restrict__ rowptr2, float* __restrict__ dis2){
  int b = blockIdx.x;
  const int* src; int n, base;
  seg_select(b, deg1, cntn, deg2, src, n, base);
  int* rp; int* cur; float* dis;
  if (b < NB1){ rp = rowptr1; cur = nullptr; dis = dis1; }
  else if (b < NB1 + NB2){ rp = rowptrn; cur = curn; dis = nullptr; }
  else { rp = rowptr2; cur = nullptr; dis = dis2; }
  int t = threadIdx.x;
  int i0 = base + t * 4;
  int v[4]; int s = 0;
  #pragma unroll
  for (int j = 0; j < 4; ++j){ int i = i0 + j; v[j] = (i < n) ? src[i] : 0; s += v[j]; }
  __shared__ int sh[256];
  sh[t] = s; __syncthreads();
  for (int off = 1; off < 256; off <<= 1){
    int add = (t >= off) ? sh[t - off] : 0;
    __syncthreads();
    sh[t] += add;
    __syncthreads();
  }
  int run = sh[t] - s + boff[b];
  #pragma unroll
  for (int j = 0; j < 4; ++j){
    int i = i0 + j;
    if (i < n){
      rp[i] = run;
      if (cur) cur[i] = run;
      if (dis) dis[i] = rsqrtf((float)v[j] + 1.0f);
      run += v[j];
    }
  }
}

// node->cluster CSR fill
__global__ void fill_n(const int* __restrict__ cluster, int* __restrict__ curn,
                       int* __restrict__ nidx){
  int v = blockIdx.x * blockDim.x + threadIdx.x;
  if (v >= N_NODES) return;
  nidx[atomicAdd(&curn[cluster[v]], 1)] = v;
}

// ---------------------------------------------------------------------------
// psrcC build: cluster c's pooled-edge list = concat of members' edge runs
// payload: src-cluster | (dst-cluster & 15) << 17
// ---------------------------------------------------------------------------
__launch_bounds__(256)
__global__ void psrc_build(const int* __restrict__ rowptrn, const int* __restrict__ nidx,
                           const int* __restrict__ rowptr1, const int* __restrict__ esrc1,
                           const int* __restrict__ cluster, const int* __restrict__ rowptr2,
                           int* __restrict__ psrcC){
  int c = blockIdx.x * 4 + (threadIdx.x >> 6);
  int l = threadIdx.x & 63;
  int mb = rowptrn[c], me = rowptrn[c + 1];
  int cnt = me - mb;                       // members per cluster (<= 64)
  int base_l = 0, d_l = 0;
  if (l < cnt){
    int v = nidx[mb + l];
    base_l = rowptr1[v];
    d_l = rowptr1[v + 1] - base_l;
  }
  int pref = d_l;                          // inclusive scan over 64 lanes
  #pragma unroll
  for (int off = 1; off < 64; off <<= 1){
    int u = __shfl_up(pref, off);
    if (l >= off) pref += u;
  }
  int total = __shfl(pref, 63);
  int wbase = rowptr2[c];
  int dbits = (c & 15) << 17;
  int iters = (total + 63) >> 6;           // uniform loop; all lanes active
  for (int k = 0; k < iters; ++k){
    int idx = k * 64 + l;
    int idxc = min(idx, total - 1);
    int m = 0;
    for (int j = 0; j < cnt; ++j){
      int pj = __shfl(pref, j);
      if (idxc >= pj) m = j + 1;
    }
    int pm = __shfl(pref, m);
    int dm = __shfl(d_l, m);
    int bm = __shfl(base_l, m);
    int e = bm + idxc - (pm - dm);
    int sc = cluster[esrc1[e] & (int)PAY_SRC_MASK];
    if (idx < total) psrcC[wbase + idx] = sc | dbits;
  }
}

// ---------------------------------------------------------------------------
// MFMA GEMM: C[M,128] = (A[M,128] @ B[128,128]) * scale[row], bf16 packed out
// ---------------------------------------------------------------------------
template<bool A_BF16>
__launch_bounds__(256)
__global__ void gemm_mfma(const void* __restrict__ Aptr, const float* __restrict__ B,
                          const float* __restrict__ scale, unsigned* __restrict__ Cmat,
                          int M){
  __shared__ __align__(16) unsigned Blds[128 * 68];
  __shared__ __align__(16) unsigned Alds[64 * 68];
  const int t = threadIdx.x;
  const int row0 = blockIdx.x * 64;

  #pragma unroll
  for (int i = 0; i < 8; ++i){
    int task = t + i * 256;
    int kp = task >> 5, nq = task & 31;
    float4 b0 = *(const float4*)&B[(2 * kp) * 128 + nq * 4];
    float4 b1 = *(const float4*)&B[(2 * kp + 1) * 128 + nq * 4];
    Blds[(nq * 4 + 0) * 68 + kp] = pack2(b0.x, b1.x);
    Blds[(nq * 4 + 1) * 68 + kp] = pack2(b0.y, b1.y);
    Blds[(nq * 4 + 2) * 68 + kp] = pack2(b0.z, b1.z);
    Blds[(nq * 4 + 3) * 68 + kp] = pack2(b0.w, b1.w);
  }
  if (A_BF16){
    const unsigned* A = (const unsigned*)Aptr;
    #pragma unroll
    for (int i = 0; i < 8; ++i){
      int idx = t + i * 256;
      int row = idx >> 5, c2 = idx & 31;
      int grow = min(row0 + row, M - 1);
      uint2 v = *(const uint2*)&A[(size_t)grow * 64 + c2 * 2];
      Alds[row * 68 + c2 * 2]     = v.x;
      Alds[row * 68 + c2 * 2 + 1] = v.y;
    }
  } else {
    const float* A = (const float*)Aptr;
    #pragma unroll
    for (int i = 0; i < 8; ++i){
      int idx = t + i * 256;
      int row = idx >> 5, k4 = idx & 31;
      int grow = min(row0 + row, M - 1);
      float4 v = *(const float4*)&A[(size_t)grow * 128 + k4 * 4];
      Alds[row * 68 + k4 * 2]     = pack2(v.x, v.y);
      Alds[row * 68 + k4 * 2 + 1] = pack2(v.z, v.w);
    }
  }
  __syncthreads();

  const int wv = t >> 6, l = t & 63, quad = l >> 4, n16 = l & 15;
  f32x4 acc[8];
  #pragma unroll
  for (int nt = 0; nt < 8; ++nt) acc[nt] = (f32x4){0.f, 0.f, 0.f, 0.f};
  const int arow = wv * 16 + n16;
  #pragma unroll
  for (int ks = 0; ks < 4; ++ks){
    bf16x8 af = *(const bf16x8*)&Alds[arow * 68 + ks * 16 + quad * 4];
    #pragma unroll
    for (int nt = 0; nt < 8; ++nt){
      bf16x8 bfr = *(const bf16x8*)&Blds[(nt * 16 + n16) * 68 + ks * 16 + quad * 4];
      acc[nt] = __builtin_amdgcn_mfma_f32_16x16x32_bf16(af, bfr, acc[nt], 0, 0, 0);
    }
  }
  #pragma unroll
  for (int nt = 0; nt < 8; ++nt){
    #pragma unroll
    for (int r = 0; r < 4; ++r){
      int row = row0 + wv * 16 + quad * 4 + r;
      float sc = scale[min(row, M - 1)];
      float v = acc[nt][r] * sc;
      float vhi = __shfl_xor(v, 1);
      if (((l & 1) == 0) && row < M)
        Cmat[(size_t)row * 64 + nt * 8 + (n16 >> 1)] = pack2(v, vhi);
    }
  }
}

// ---------------------------------------------------------------------------
// MFMA CSR conv, block-cooperative: one BLOCK (4 waves) per 16 dst rows.
// Wave wv owns chunks wv, wv+4, wv+8, ... (32 edges each), keeping the
// per-wave gather->LDS->MFMA pipeline; partial sums are combined across
// waves via an LDS f32 reduction, epilogue split 2 column-tiles per wave.
// This multiplies wave-parallelism 4x vs the round-2 version (the counters
// showed conv2/3 at 1563 waves total -> everything latency-starved).
// Self-loop = 16 appended virtual edges (weight 1):
//   out = relu(dis[row] * (sum_e Ts[src] + Ts[row]) + b)
// ---------------------------------------------------------------------------
constexpr int BSTR = 17;   // LDS uints per feature row (odd -> banks spread)

__launch_bounds__(256, 4)
__global__ void conv_mfma(const unsigned* __restrict__ Ts, const float* __restrict__ dis,
                          const int* __restrict__ rowptr, const int* __restrict__ epay,
                          const float* __restrict__ bias, unsigned* __restrict__ Hout,
                          int M){
  __shared__ unsigned Blds[4][128 * BSTR];
  const int t = threadIdx.x, wv = t >> 6, l = t & 63;
  const int base = blockIdx.x * 16;
  const int n16 = l & 15, quad = l >> 4, k32 = l & 31;
  const int beg = rowptr[base];
  const int end = rowptr[min(base + 16, M)];
  const int cnt = end - beg;
  const int selfN = min(16, M - base);
  const int total = cnt + selfN;
  const int nch = (total + 31) >> 5;
  unsigned* Bl = &Blds[wv][0];

  f32x4 acc[8];
  #pragma unroll
  for (int nt = 0; nt < 8; ++nt) acc[nt] = (f32x4){0.f, 0.f, 0.f, 0.f};

  // clamped payload fetch (uniform, non-divergent; OOB lanes decode to self/null)
  auto pay_load = [&](int ch) -> int {
    if (cnt == 0) return 0;
    int ke = min(ch * 32 + k32, cnt - 1);
    return epay[beg + ke];
  };
  auto decode = [&](int ch, int p, int& src, int& d){
    int ke = ch * 32 + k32;
    if (ke < cnt){ src = p & (int)PAY_SRC_MASK; d = (p >> 17) & 15; }
    else {
      int sd = ke - cnt;
      d   = (sd < selfN) ? sd : 31;          // 31 never matches a row -> weight 0
      src = (sd < selfN) ? (base + sd) : 0;  // safe dummy row for OOB lanes
    }
  };
  // batch-issue all 8 gather loads (kept in flight together)
  auto issue = [&](int src, uint4* u){
    int s[8];
    #pragma unroll
    for (int i = 0; i < 4; ++i){
      int pp = quad + i * 4;
      s[2 * i]     = __shfl(src, 2 * pp);
      s[2 * i + 1] = __shfl(src, 2 * pp + 1);
    }
    #pragma unroll
    for (int i = 0; i < 8; ++i)
      u[i] = *(const uint4*)&Ts[(size_t)s[i] * 64 + n16 * 4];
  };
  // stage 32 gathered rows into LDS as [feat][edge-pair] uints
  auto stage = [&](const uint4* u){
    #pragma unroll
    for (int i = 0; i < 4; ++i){
      int pp = quad + i * 4;
      uint4 u0 = u[2 * i], u1 = u[2 * i + 1];
      unsigned* wp = Bl + (n16 * 8) * BSTR + pp;
      wp[0 * BSTR] = __builtin_amdgcn_perm(u1.x, u0.x, 0x05040100u);
      wp[1 * BSTR] = __builtin_amdgcn_perm(u1.x, u0.x, 0x07060302u);
      wp[2 * BSTR] = __builtin_amdgcn_perm(u1.y, u0.y, 0x05040100u);
      wp[3 * BSTR] = __builtin_amdgcn_perm(u1.y, u0.y, 0x07060302u);
      wp[4 * BSTR] = __builtin_amdgcn_perm(u1.z, u0.z, 0x05040100u);
      wp[5 * BSTR] = __builtin_amdgcn_perm(u1.z, u0.z, 0x07060302u);
      wp[6 * BSTR] = __builtin_amdgcn_perm(u1.w, u0.w, 0x05040100u);
      wp[7 * BSTR] = __builtin_amdgcn_perm(u1.w, u0.w, 0x07060302u);
    }
  };
  // one-hot A + B fragments + 8 MFMAs for the chunk staged in LDS
  auto compute = [&](int d){
    union { unsigned u[4]; bf16x8 v; } af;
    #pragma unroll
    for (int jj = 0; jj < 4; ++jj){
      int d0 = __shfl(d, quad * 8 + 2 * jj);
      int d1 = __shfl(d, quad * 8 + 2 * jj + 1);
      af.u[jj] = (d0 == n16 ? 0x3F80u : 0u) | (d1 == n16 ? 0x3F800000u : 0u);
    }
    #pragma unroll
    for (int nt = 0; nt < 8; ++nt){
      union { unsigned u[4]; bf16x8 v; } bf;
      const unsigned* rp = Bl + (nt * 16 + n16) * BSTR + quad * 4;
      bf.u[0] = rp[0]; bf.u[1] = rp[1]; bf.u[2] = rp[2]; bf.u[3] = rp[3];
      acc[nt] = __builtin_amdgcn_mfma_f32_16x16x32_bf16(af.v, bf.v, acc[nt], 0, 0, 0);
    }
  };

  // ---- pipelined wave-strided chunk loop (chunks wv, wv+4, ...) ----
  if (wv < nch){
    uint4 u[8];
    int p = pay_load(wv);
    int src_c, d_c;
    decode(wv, p, src_c, d_c);
    issue(src_c, u);                 // first chunk gathers in flight
    int p_nxt = pay_load(wv + 4);    // next chunk payload in flight (clamped-safe)
    for (int ch = wv; ch < nch; ch += 4){
      stage(u);                      // waits vmcnt on chunk ch gathers
      int d_keep = d_c;
      if (ch + 4 < nch){
        int s_n, d_n;
        decode(ch + 4, p_nxt, s_n, d_n);
        issue(s_n, u);               // next gathers in flight under compute
        p_nxt = pay_load(ch + 8);
        d_c = d_n;
      }
      compute(d_keep);               // ds_read + MFMA for chunk ch
    }
  }

  // ---- cross-wave reduction: each wave dumps its f32 partials, then
  //      wave wv finishes columns nt = 2*wv, 2*wv+1 ----
  constexpr int WSTR = 128 * BSTR;   // 2176 uints per wave region (need 2048)
  float* F = (float*)&Blds[0][0];
  float* myF = F + wv * WSTR;
  #pragma unroll
  for (int nt = 0; nt < 8; ++nt){
    #pragma unroll
    for (int r = 0; r < 4; ++r)
      myF[(nt * 4 + r) * 64 + l] = acc[nt][r];
  }
  __syncthreads();
  #pragma unroll
  for (int nt2 = 0; nt2 < 2; ++nt2){
    int nt = wv * 2 + nt2;
    float bvv = bias[nt * 16 + n16];
    #pragma unroll
    for (int r = 0; r < 4; ++r){
      int row = base + quad * 4 + r;
      int idx = (nt * 4 + r) * 64 + l;
      float s = F[idx] + F[WSTR + idx] + F[2 * WSTR + idx] + F[3 * WSTR + idx];
      float dsc = dis[min(row, M - 1)];
      float v = fmaxf(fmaf(dsc, s, bvv), 0.f);
      float vhi = __shfl_xor(v, 1);
      if (((l & 1) == 0) && row < M)
        Hout[(size_t)row * 64 + nt * 8 + (n16 >> 1)] = pack2(v, vhi);
    }
  }
}

// cluster mean pool + batch_p, quarter-wave uint4 gather
__launch_bounds__(256)
__global__ void cluster_gather(const unsigned* __restrict__ h1, const int* __restrict__ rowptrn,
                               const int* __restrict__ nidx, const int* __restrict__ batch,
                               unsigned* __restrict__ hp, int* __restrict__ batchp){
  int c = blockIdx.x * 4 + (threadIdx.x >> 6);
  int l = threadIdx.x & 63;
  int q = l & 15, h = l >> 4;
  int mb = rowptrn[c], me = rowptrn[c + 1];
  float acc[8] = {0.f,0.f,0.f,0.f,0.f,0.f,0.f,0.f};
  int vmax = -1;
  for (int base = mb; base < me; base += 64){
    int n = min(64, me - base);
    int vid = nidx[base + min(l, n - 1)];
    if (l < n) vmax = max(vmax, vid);
    int j = 0;
    for (; j + 8 <= n; j += 8){
      int s0 = __shfl(vid, j + h);
      int s1 = __shfl(vid, j + 4 + h);
      uint4 u0 = *(const uint4*)&h1[(size_t)s0 * 64 + q * 4];
      uint4 u1 = *(const uint4*)&h1[(size_t)s1 * 64 + q * 4];
      acc[0] += bf16lo(u0.x); acc[1] += bf16hi(u0.x);
      acc[2] += bf16lo(u0.y); acc[3] += bf16hi(u0.y);
      acc[4] += bf16lo(u0.z); acc[5] += bf16hi(u0.z);
      acc[6] += bf16lo(u0.w); acc[7] += bf16hi(u0.w);
      acc[0] += bf16lo(u1.x); acc[1] += bf16hi(u1.x);
      acc[2] += bf16lo(u1.y); acc[3] += bf16hi(u1.y);
      acc[4] += bf16lo(u1.z); acc[5] += bf16hi(u1.z);
      acc[6] += bf16lo(u1.w); acc[7] += bf16hi(u1.w);
    }
    for (; j < n; j += 4){
      int ei = j + h;
      int s = __shfl(vid, min(ei, n - 1));
      uint4 u = *(const uint4*)&h1[(size_t)s * 64 + q * 4];
      if (ei < n){
        acc[0] += bf16lo(u.x); acc[1] += bf16hi(u.x);
        acc[2] += bf16lo(u.y); acc[3] += bf16hi(u.y);
        acc[4] += bf16lo(u.z); acc[5] += bf16hi(u.z);
        acc[6] += bf16lo(u.w); acc[7] += bf16hi(u.w);
      }
    }
  }
  #pragma unroll
  for (int k = 0; k < 8; ++k){
    acc[k] += __shfl_xor(acc[k], 16);
    acc[k] += __shfl_xor(acc[k], 32);
  }
  #pragma unroll
  for (int off = 32; off > 0; off >>= 1) vmax = max(vmax, __shfl_xor(vmax, off));
  float inv = 1.0f / (float)max(me - mb, 1);
  if (h == 0){
    uint4 o;
    o.x = pack2(acc[0] * inv, acc[1] * inv);
    o.y = pack2(acc[2] * inv, acc[3] * inv);
    o.z = pack2(acc[4] * inv, acc[5] * inv);
    o.w = pack2(acc[6] * inv, acc[7] * inv);
    *(uint4*)&hp[(size_t)c * 64 + q * 4] = o;
  }
  if (l == 0) batchp[c] = (vmax >= 0) ? batch[vmax] : 0;  // batch sorted by node id
}

__global__ void cntp_kernel(const int* __restrict__ batchp, int* __restrict__ cntp){
  int c = blockIdx.x * blockDim.x + threadIdx.x;
  if (c < N_CLUST) atomicAdd(&cntp[batchp[c]], 1);
}

// graph -> cluster CSR: scan cntp (64 entries) + cursor fill
__global__ void scan_cntp(const int* __restrict__ cntp, int* __restrict__ gbasep,
                          int* __restrict__ curp){
  int t = threadIdx.x;                 // 64 threads
  int v = cntp[t];
  int s = v;
  for (int off = 1; off < 64; off <<= 1){
    int u = __shfl_up(s, off);
    if (t >= off) s += u;
  }
  gbasep[t] = s - v; curp[t] = s - v;
  if (t == 63) gbasep[64] = s;
}

__global__ void fill_c(const int* __restrict__ batchp, int* __restrict__ curp,
                       int* __restrict__ cidx){
  int c = blockIdx.x * blockDim.x + threadIdx.x;
  if (c < N_CLUST) cidx[atomicAdd(&curp[batchp[c]], 1)] = c;
}

// ---------------------------------------------------------------------------
__global__ void graph_bounds(const int* __restrict__ batch, int* __restrict__ gstart){
  int g = threadIdx.x;
  if (g > N_GRAPH) return;
  int lo = 0, hi = N_NODES;
  while (lo < hi){ int mid = (lo + hi) >> 1; if (batch[mid] < g) lo = mid + 1; else hi = mid; }
  gstart[g] = lo;
}

__device__ __forceinline__ void atomicMaxPosF(float* addr, float v){
  atomicMax((int*)addr, __float_as_int(v));
}

// pre-pool gather: graph g's rows are contiguous [gstart[g], gstart[g+1])
constexpr int PRE_SPLIT = 8;
__launch_bounds__(256)
__global__ void pre_pool_g(const unsigned* __restrict__ h1, const int* __restrict__ gstart,
                           float* __restrict__ psum, float* __restrict__ pmax){
  int g = blockIdx.x / PRE_SPLIT, sp = blockIdx.x % PRE_SPLIT;
  int t = threadIdx.x, w = t >> 6, l = t & 63;
  int s0 = gstart[g], s1 = gstart[g + 1];
  int n = s1 - s0;
  int per = (n + PRE_SPLIT - 1) / PRE_SPLIT;
  int b0 = s0 + sp * per, b1 = min(b0 + per, s1);
  float2 a0{0.f,0.f}, a1{0.f,0.f}, a2{0.f,0.f}, a3{0.f,0.f};
  float2 mx{0.f,0.f};
  int i = b0 + w;
  for (; i + 12 < b1; i += 16){
    unsigned u0 = h1[(size_t)(i     ) * 64 + l];
    unsigned u1 = h1[(size_t)(i +  4) * 64 + l];
    unsigned u2 = h1[(size_t)(i +  8) * 64 + l];
    unsigned u3 = h1[(size_t)(i + 12) * 64 + l];
    float f0x = bf16lo(u0), f0y = bf16hi(u0);
    float f1x = bf16lo(u1), f1y = bf16hi(u1);
    float f2x = bf16lo(u2), f2y = bf16hi(u2);
    float f3x = bf16lo(u3), f3y = bf16hi(u3);
    a0.x += f0x; a0.y += f0y; a1.x += f1x; a1.y += f1y;
    a2.x += f2x; a2.y += f2y; a3.x += f3x; a3.y += f3y;
    mx.x = fmaxf(fmaxf(mx.x, fmaxf(f0x, f1x)), fmaxf(f2x, f3x));
    mx.y = fmaxf(fmaxf(mx.y, fmaxf(f0y, f1y)), fmaxf(f2y, f3y));
  }
  for (; i < b1; i += 4){
    unsigned u = h1[(size_t)i * 64 + l];
    float fx = bf16lo(u), fy = bf16hi(u);
    a0.x += fx; a0.y += fy;
    mx.x = fmaxf(mx.x, fx); mx.y = fmaxf(mx.y, fy);
  }
  __shared__ float2 ssum[4][64], smax[4][64];
  ssum[w][l] = { a0.x + a1.x + a2.x + a3.x, a0.y + a1.y + a2.y + a3.y };
  smax[w][l] = mx;
  __syncthreads();
  if (w == 0){
    float2 S = ssum[0][l], M = smax[0][l];
    #pragma unroll
    for (int k = 1; k < 4; ++k){
      S.x += ssum[k][l].x; S.y += ssum[k][l].y;
      M.x = fmaxf(M.x, smax[k][l].x); M.y = fmaxf(M.y, smax[k][l].y);
    }
    atomicAdd(&psum[g * 128 + 2 * l], S.x);
    atomicAdd(&psum[g * 128 + 2 * l + 1], S.y);
    atomicMaxPosF(&pmax[g * 128 + 2 * l], M.x);
    atomicMaxPosF(&pmax[g * 128 + 2 * l + 1], M.y);
  }
}

// post-pool gather via graph->cluster CSR
constexpr int POST_SPLIT = 4;
__launch_bounds__(256)
__global__ void post_pool_g(const unsigned* __restrict__ hp3, const int* __restrict__ gbasep,
                            const int* __restrict__ cidx,
                            float* __restrict__ psum, float* __restrict__ pmax){
  int g = blockIdx.x / POST_SPLIT, sp = blockIdx.x % POST_SPLIT;
  int t = threadIdx.x, w = t >> 6, l = t & 63;
  int s0 = gbasep[g], s1 = gbasep[g + 1];
  int n = s1 - s0;
  int per = (n + POST_SPLIT * 4 - 1) / (POST_SPLIT * 4);
  int b0 = s0 + (sp * 4 + w) * per, b1 = min(b0 + per, s1);
  float2 a0{0.f,0.f}, a1{0.f,0.f}, a2{0.f,0.f}, a3{0.f,0.f};
  float2 mx{0.f,0.f};
  for (int base = b0; base < b1; base += 64){
    int nn = min(64, b1 - base);
    int cid = cidx[base + min(l, nn - 1)];
    int j = 0;
    for (; j + 4 <= nn; j += 4){
      int c0 = __shfl(cid, j);
      int c1 = __shfl(cid, j + 1);
      int c2 = __shfl(cid, j + 2);
      int c3 = __shfl(cid, j + 3);
      unsigned u0 = hp3[(size_t)c0 * 64 + l];
      unsigned u1 = hp3[(size_t)c1 * 64 + l];
      unsigned u2 = hp3[(size_t)c2 * 64 + l];
      unsigned u3 = hp3[(size_t)c3 * 64 + l];
      float f0x = bf16lo(u0), f0y = bf16hi(u0);
      float f1x = bf16lo(u1), f1y = bf16hi(u1);
      float f2x = bf16lo(u2), f2y = bf16hi(u2);
      float f3x = bf16lo(u3), f3y = bf16hi(u3);
      a0.x += f0x; a0.y += f0y; a1.x += f1x; a1.y += f1y;
      a2.x += f2x; a2.y += f2y; a3.x += f3x; a3.y += f3y;
      mx.x = fmaxf(fmaxf(mx.x, fmaxf(f0x, f1x)), fmaxf(f2x, f3x));
      mx.y = fmaxf(fmaxf(mx.y, fmaxf(f0y, f1y)), fmaxf(f2y, f3y));
    }
    for (; j < nn; ++j){
      int c = __shfl(cid, j);
      unsigned u = hp3[(size_t)c * 64 + l];
      float fx = bf16lo(u), fy = bf16hi(u);
      a0.x += fx; a0.y += fy;
      mx.x = fmaxf(mx.x, fx); mx.y = fmaxf(mx.y, fy);
    }
  }
  __shared__ float2 ssum[4][64], smax[4][64];
  ssum[w][l] = { a0.x + a1.x + a2.x + a3.x, a0.y + a1.y + a2.y + a3.y };
  smax[w][l] = mx;
  __syncthreads();
  if (w == 0){
    float2 S = ssum[0][l], M = smax[0][l];
    #pragma unroll
    for (int k = 1; k < 4; ++k){
      S.x += ssum[k][l].x; S.y += ssum[k][l].y;
      M.x = fmaxf(M.x, smax[k][l].x); M.y = fmaxf(M.y, smax[k][l].y);
    }
    atomicAdd(&psum[g * 128 + 2 * l], S.x);
    atomicAdd(&psum[g * 128 + 2 * l + 1], S.y);
    atomicMaxPosF(&pmax[g * 128 + 2 * l], M.x);
    atomicMaxPosF(&pmax[g * 128 + 2 * l + 1], M.y);
  }
}

__launch_bounds__(128)
__global__ void head_kernel(const float* __restrict__ psum, const float* __restrict__ pmax,
                            const float* __restrict__ postsum, const float* __restrict__ postmax,
                            const int* __restrict__ gstart, const int* __restrict__ cntp,
                            const float* __restrict__ l1w, const float* __restrict__ l1b,
                            const float* __restrict__ l2w, const float* __restrict__ l2b,
                            float* __restrict__ out){
  int g = blockIdx.x, t = threadIdx.x;
  __shared__ float z[512];
  __shared__ float a[128];
  __shared__ float logits[16];
  __shared__ float lse_s;
  float cpre  = (float)max(gstart[g + 1] - gstart[g], 1);
  float cpost = fmaxf((float)cntp[g], 1.0f);
  z[t]       = psum[g * 128 + t] / cpre;
  z[128 + t] = pmax[g * 128 + t];
  z[256 + t] = postsum[g * 128 + t] / cpost;
  z[384 + t] = postmax[g * 128 + t];
  __syncthreads();
  float acc = l1b[t];
  #pragma unroll 8
  for (int k = 0; k < 512; ++k) acc = fmaf(z[k], l1w[k * 128 + t], acc);
  a[t] = fmaxf(acc, 0.f);
  __syncthreads();
  if (t < NCLSN){
    float s2 = l2b[t];
    for (int k = 0; k < 128; ++k) s2 = fmaf(a[k], l2w[k * NCLSN + t], s2);
    logits[t] = s2;
  }
  __syncthreads();
  if (t == 0){
    float m = logits[0];
    for (int c = 1; c < NCLSN; ++c) m = fmaxf(m, logits[c]);
    float s = 0.f;
    for (int c = 0; c < NCLSN; ++c) s += expf(logits[c] - m);
    lse_s = m + logf(s);
  }
  __syncthreads();
  if (t < NCLSN) out[g * NCLSN + t] = logits[t] - lse_s;
}

// ---------------------------------------------------------------------------
extern "C" void kernel_launch(void* const* d_in, const int* in_sizes, int n_in,
                              void* d_out, int out_size, void* d_ws, size_t ws_size,
                              hipStream_t stream){
  const float* x       = (const float*)d_in[0];
  const int*   ei      = (const int*)  d_in[1];
  const int*   batch   = (const int*)  d_in[2];
  const int*   cluster = (const int*)  d_in[3];
  const float* W1      = (const float*)d_in[6];
  const float* b1      = (const float*)d_in[7];
  const float* W2      = (const float*)d_in[8];
  const float* b2      = (const float*)d_in[9];
  const float* W3      = (const float*)d_in[10];
  const float* b3      = (const float*)d_in[11];
  const float* l1w     = (const float*)d_in[12];
  const float* l1b     = (const float*)d_in[13];
  const float* l2w     = (const float*)d_in[14];
  const float* l2b     = (const float*)d_in[15];
  float* out = (float*)d_out;

  char* base = (char*)d_ws;
  size_t off = 0;
  auto alloc = [&](size_t bytes) -> char* {
    char* p = base + off;
    off += (bytes + 255) & ~size_t(255);
    return p;
  };
  // ---- zero zone (one memset) ----
  char*  zbase  = base + off;
  int*   cntn   = (int*)  alloc((size_t)N_CLUST * 4);
  int*   deg2   = (int*)  alloc((size_t)N_CLUST * 4);
  int*   cntp   = (int*)  alloc((size_t)N_GRAPH * 4);
  float* pre_s  = (float*)alloc((size_t)N_GRAPH * 128 * 4);
  float* pre_m  = (float*)alloc((size_t)N_GRAPH * 128 * 4);
  float* post_s = (float*)alloc((size_t)N_GRAPH * 128 * 4);
  float* post_m = (float*)alloc((size_t)N_GRAPH * 128 * 4);
  size_t zsize = off;
  // ---- plain buffers (bf16 feature rows: 64 uints per row) ----
  unsigned* Ts1   = (unsigned*)alloc((size_t)N_NODES * 64 * 4);  // later aliased
  unsigned* h1    = (unsigned*)alloc((size_t)N_NODES * 64 * 4);  // stage buf aliases here
  int*   esrc1   = (int*)  alloc((size_t)N_EDGES * 4);
  int*   psrcC   = (int*)  alloc((size_t)N_EDGES * 4);
  int*   deg1    = (int*)  alloc((size_t)N_NODES * 4);
  int*   rowptr1 = (int*)  alloc((size_t)(N_NODES + 1) * 4);
  int*   rowptrn = (int*)  alloc((size_t)(N_CLUST + 1) * 4);
  int*   curn    = (int*)  alloc((size_t)N_CLUST * 4);
  int*   rowptr2 = (int*)  alloc((size_t)(N_CLUST + 1) * 4);
  int*   nidx    = (int*)  alloc((size_t)N_NODES * 4);
  float* dis1    = (float*)alloc((size_t)N_NODES * 4);
  float* dis2    = (float*)alloc((size_t)N_CLUST * 4);
  int*   batchp  = (int*)  alloc((size_t)N_CLUST * 4);
  int*   gstart  = (int*)  alloc((size_t)(N_GRAPH + 1) * 4);
  int*   bsum    = (int*)  alloc((size_t)NBT * 4);
  int*   boff    = (int*)  alloc((size_t)NBT * 4);
  int*   gcnt1   = (int*)  alloc((size_t)NBKT1 * 4);
  int*   gbase1  = (int*)  alloc((size_t)NBKT1 * 4);
  int*   bhist   = (int*)  alloc((size_t)NEB * NBKT1 * 4);
  int*   boffs   = (int*)  alloc((size_t)NEB * NBKT1 * 4);
  int*   gbasep  = (int*)  alloc((size_t)(N_GRAPH + 1) * 4);
  int*   curp    = (int*)  alloc((size_t)N_GRAPH * 4);
  int*   cidx    = (int*)  alloc((size_t)N_CLUST * 4);
  // stage buffer aliases the (not-yet-written) h1 region (6.4 MB <= 25.6 MB)
  unsigned int* stage1 = (unsigned int*)h1;
  // aliases into Ts1 (dead after conv1): 4 x 25000*64 uints = exactly Ts1 size
  unsigned* hp  = Ts1;
  unsigned* Ts2 = Ts1 + (size_t)N_CLUST * 64;
  unsigned* hp2 = Ts1 + (size_t)2 * N_CLUST * 64;
  unsigned* hp3 = Ts1 + (size_t)3 * N_CLUST * 64;
  unsigned* Ts3 = Ts2;

  (void)in_sizes; (void)n_in; (void)out_size; (void)ws_size;

  hipMemsetAsync(zbase, 0, zsize, stream);

  // ---- radix node-CSR build ----
  count_kernel  <<<NEB, 1024, 0, stream>>>(ei, bhist);
  colscan       <<<NBKT1, 512, 0, stream>>>(bhist, boffs, gcnt1);
  bucket_scan   <<<1, 256, 0, stream>>>(gcnt1, gbase1);
  scatter_kernel<<<NEB, 1024, 0, stream>>>(ei, gbase1, boffs, stage1);
  bucket_sort   <<<NBKT1, 1024, 0, stream>>>(stage1, gbase1, gcnt1, esrc1, deg1);
  node_prep<<<(N_NODES + 255) / 256, 256, 0, stream>>>(cluster, deg1, cntn, deg2);
  block_sums <<<NBT, 256, 0, stream>>>(deg1, cntn, deg2, bsum);
  scan_bsums <<<1, 256, 0, stream>>>(bsum, boff, rowptr1, rowptrn, rowptr2);
  scan_final <<<NBT, 256, 0, stream>>>(deg1, cntn, deg2, boff,
                                       rowptr1, dis1, rowptrn, curn, rowptr2, dis2);
  fill_n<<<(N_NODES + 255) / 256, 256, 0, stream>>>(cluster, curn, nidx);
  psrc_build<<<N_CLUST / 4, 256, 0, stream>>>(rowptrn, nidx, rowptr1, esrc1,
                                              cluster, rowptr2, psrcC);

  // conv1 (MFMA one-hot SpMM over node CSR, one block per 16-row group)
  constexpr int NG1 = N_NODES / 16;               // 6250 groups
  constexpr int NG2 = (N_CLUST + 15) / 16;        // 1563 groups
  gemm_mfma<false><<<(N_NODES + 63) / 64, 256, 0, stream>>>(x, W1, dis1, Ts1, N_NODES);
  conv_mfma<<<NG1, 256, 0, stream>>>(Ts1, dis1, rowptr1, esrc1, b1, h1, N_NODES);

  // pre pools (gather over contiguous sorted-batch ranges)
  graph_bounds<<<1, 128, 0, stream>>>(batch, gstart);
  pre_pool_g<<<N_GRAPH * PRE_SPLIT, 256, 0, stream>>>(h1, gstart, pre_s, pre_m);

  // cluster mean pool + batch_p + cntp + graph->cluster CSR
  cluster_gather<<<N_CLUST / 4, 256, 0, stream>>>(h1, rowptrn, nidx, batch, hp, batchp);
  cntp_kernel<<<(N_CLUST + 255) / 256, 256, 0, stream>>>(batchp, cntp);
  scan_cntp<<<1, 64, 0, stream>>>(cntp, gbasep, curp);
  fill_c<<<(N_CLUST + 255) / 256, 256, 0, stream>>>(batchp, curp, cidx);

  // conv2
  gemm_mfma<true><<<(N_CLUST + 63) / 64, 256, 0, stream>>>(hp, W2, dis2, Ts2, N_CLUST);
  conv_mfma<<<NG2, 256, 0, stream>>>(Ts2, dis2, rowptr2, psrcC, b2, hp2, N_CLUST);

  // conv3
  gemm_mfma<true><<<(N_CLUST + 63) / 64, 256, 0, stream>>>(hp2, W3, dis2, Ts3, N_CLUST);
  conv_mfma<<<NG2, 256, 0, stream>>>(Ts3, dis2, rowptr2, psrcC, b3, hp3, N_CLUST);

  // post pools (gather via graph->cluster CSR) + head
  post_pool_g<<<N_GRAPH * POST_SPLIT, 256, 0, stream>>>(hp3, gbasep, cidx, post_s, post_m);
  head_kernel<<<N_GRAPH, 128, 0, stream>>>(pre_s, pre_m, post_s, post_m, gstart, cntp,
                                           l1w, l1b, l2w, l2b, out);
}

// Round 4
// 538.286 us; speedup vs baseline: 1.1674x; 1.0895x over previous
//
#include <hip/hip_runtime.h>

constexpr int N_NODES = 100000;
constexpr int N_EDGES = 1600000;
constexpr int N_CLUST = 25000;
constexpr int N_GRAPH = 64;
constexpr int NCLSN   = 10;

// bucket decomposition for the radix node-CSR build
constexpr int BKT1_SHIFT = 9;                       // node-dst buckets of 512 ids
constexpr int NBKT1 = (N_NODES + 511) / 512;        // 196
constexpr int EPB = 4096;                           // edges per block (count/scatter)
constexpr int NEB = (N_EDGES + EPB - 1) / EPB;      // 391
constexpr int SORT_CAP = 12288;                     // LDS staging cap (mean 8163, sd ~90)

// edge payload layout (esrc1 / psrcC): bits [16:0] = src id, bits [20:17] = dst & 15
// (kept for a possible MFMA retry; conv_csr masks with PAY_SRC_MASK)
constexpr unsigned PAY_SRC_MASK = 0x1FFFFu;

// scan partitioning: 1024 elements per block, three concatenated segments
constexpr int SCAN_BPB = 1024;
constexpr int NB1 = (N_NODES + SCAN_BPB - 1) / SCAN_BPB;  // 98
constexpr int NB2 = (N_CLUST + SCAN_BPB - 1) / SCAN_BPB;  // 25
constexpr int NB3 = (N_CLUST + SCAN_BPB - 1) / SCAN_BPB;  // 25
constexpr int NBT = NB1 + NB2 + NB3;                      // 148

// ---- bf16 pack/unpack helpers (features stored as packed pairs in uint) ----
__device__ __forceinline__ float bf16lo(unsigned u){ return __uint_as_float(u << 16); }
__device__ __forceinline__ float bf16hi(unsigned u){ return __uint_as_float(u & 0xffff0000u); }
__device__ __forceinline__ unsigned bf16_rne(float f){
  unsigned u = __float_as_uint(f);
  return (u + 0x7fffu + ((u >> 16) & 1u)) >> 16;
}
__device__ __forceinline__ unsigned pack2(float lo, float hi){
  return bf16_rne(lo) | (bf16_rne(hi) << 16);
}

typedef short bf16x8 __attribute__((ext_vector_type(8)));
typedef float f32x4  __attribute__((ext_vector_type(4)));

// ---------------------------------------------------------------------------
// radix node-CSR build, phase 1: per-block bucket histograms (no global atomics)
// ---------------------------------------------------------------------------
__launch_bounds__(1024)
__global__ void count_kernel(const int* __restrict__ ei, int* __restrict__ bhist){
  __shared__ int h1c[NBKT1];
  int t = threadIdx.x;
  for (int i = t; i < NBKT1; i += 1024) h1c[i] = 0;
  __syncthreads();
  int e0 = blockIdx.x * EPB;
  #pragma unroll
  for (int i = 0; i < EPB / 1024; ++i){
    int e = e0 + i * 1024 + t;
    if (e < N_EDGES) atomicAdd(&h1c[ei[N_EDGES + e] >> BKT1_SHIFT], 1);
  }
  __syncthreads();
  for (int i = t; i < NBKT1; i += 1024) bhist[blockIdx.x * NBKT1 + i] = h1c[i];
}

// phase 2a: column scan of the histogram matrix -> per-(block,bucket) offsets
__launch_bounds__(512)
__global__ void colscan(const int* __restrict__ bhist, int* __restrict__ boffs,
                        int* __restrict__ gcnt1){
  __shared__ int s[512];
  int i = blockIdx.x;                 // bucket
  int t = threadIdx.x;                // edge-block index
  int v = (t < NEB) ? bhist[t * NBKT1 + i] : 0;
  s[t] = v; __syncthreads();
  for (int o = 1; o < 512; o <<= 1){
    int a = (t >= o) ? s[t - o] : 0;
    __syncthreads(); s[t] += a; __syncthreads();
  }
  if (t < NEB) boffs[t * NBKT1 + i] = s[t] - v;   // exclusive within column
  if (t == 511) gcnt1[i] = s[511];
}

// phase 2b: bucket bases (prefix over 196 totals)
__launch_bounds__(256)
__global__ void bucket_scan(const int* __restrict__ gcnt1, int* __restrict__ gbase1){
  __shared__ int s[256];
  int t = threadIdx.x;
  int v = (t < NBKT1) ? gcnt1[t] : 0;
  s[t] = v; __syncthreads();
  for (int off = 1; off < 256; off <<= 1){
    int a = (t >= off) ? s[t - off] : 0;
    __syncthreads(); s[t] += a; __syncthreads();
  }
  if (t < NBKT1) gbase1[t] = s[t] - v;
}

// phase 3: single-pass scatter into pre-reserved runs (no global atomics)
__launch_bounds__(1024)
__global__ void scatter_kernel(const int* __restrict__ ei, const int* __restrict__ gbase1,
                               const int* __restrict__ boffs, unsigned int* __restrict__ stage1){
  __shared__ int gb1[NBKT1];
  __shared__ int cur[NBKT1];
  int t = threadIdx.x, b = blockIdx.x;
  for (int i = t; i < NBKT1; i += 1024){
    gb1[i] = gbase1[i] + boffs[b * NBKT1 + i];
    cur[i] = 0;
  }
  __syncthreads();
  int e0 = b * EPB;
  #pragma unroll
  for (int i = 0; i < EPB / 1024; ++i){
    int e = e0 + i * 1024 + t;
    if (e < N_EDGES){
      int src = ei[e], dst = ei[N_EDGES + e];
      int bk = dst >> BKT1_SHIFT;
      int r = atomicAdd(&cur[bk], 1);
      stage1[gb1[bk] + r] = ((unsigned)(dst & 511) << 17) | (unsigned)src;
    }
  }
}

// phase 4: per-bucket LDS counting sort + coalesced degree writes (1024 thr)
// payload keeps bits [20:17] = dst & 15 (conv_csr masks them off)
__launch_bounds__(1024)
__global__ void bucket_sort(const unsigned int* __restrict__ stage, const int* __restrict__ gbase,
                            const int* __restrict__ gcnt, int* __restrict__ outpay,
                            int* __restrict__ deg){
  __shared__ int cnt[512], off[512];
  __shared__ int sorted[SORT_CAP];
  int b = blockIdx.x, t = threadIdx.x;
  int base = gbase[b], n = gcnt[b];
  if (t < 512) cnt[t] = 0;
  __syncthreads();
  for (int i = t; i < n; i += 1024) atomicAdd(&cnt[stage[base + i] >> 17], 1);
  __syncthreads();
  if (t < 512){
    int idx = b * 512 + t;
    if (idx < N_NODES) deg[idx] = cnt[t];
    off[t] = cnt[t];
  }
  __syncthreads();
  for (int s = 1; s < 512; s <<= 1){
    int v = 0;
    if (t < 512 && t >= s) v = off[t - s];
    __syncthreads();
    if (t < 512) off[t] += v;
    __syncthreads();
  }
  if (t < 512) off[t] -= cnt[t];       // exclusive cursors
  __syncthreads();
  if (n <= SORT_CAP){
    for (int i = t; i < n; i += 1024){
      unsigned w = stage[base + i];
      int r = atomicAdd(&off[w >> 17], 1);
      sorted[r] = (int)(w & 0x1FFFFFu);   // src | (dst&15)<<17
    }
    __syncthreads();
    for (int i = t; i < n; i += 1024) outpay[base + i] = sorted[i];
  } else {  // never expected; correct fallback
    for (int i = t; i < n; i += 1024){
      unsigned w = stage[base + i];
      int r = atomicAdd(&off[w >> 17], 1);
      outpay[base + r] = (int)(w & 0x1FFFFFu);
    }
  }
}

// per-node: cluster membership count + cluster in-degree (sum of member deg1)
__global__ void node_prep(const int* __restrict__ cluster, const int* __restrict__ deg1,
                          int* __restrict__ cntn, int* __restrict__ deg2){
  int v = blockIdx.x * blockDim.x + threadIdx.x;
  if (v < N_NODES){
    int c = cluster[v];
    atomicAdd(&cntn[c], 1);
    atomicAdd(&deg2[c], deg1[v]);
  }
}

// ---------------------------------------------------------------------------
// device-wide 3-segment exclusive scan
// ---------------------------------------------------------------------------
__device__ __forceinline__ void seg_select(int b, const int* deg1, const int* cntn,
                                           const int* deg2, const int*& src, int& n, int& base){
  if (b < NB1){ src = deg1; n = N_NODES; base = b * SCAN_BPB; }
  else if (b < NB1 + NB2){ src = cntn; n = N_CLUST; base = (b - NB1) * SCAN_BPB; }
  else { src = deg2; n = N_CLUST; base = (b - NB1 - NB2) * SCAN_BPB; }
}

__launch_bounds__(256)
__global__ void block_sums(const int* __restrict__ deg1, const int* __restrict__ cntn,
                           const int* __restrict__ deg2, int* __restrict__ bsum){
  int b = blockIdx.x;
  const int* src; int n, base;
  seg_select(b, deg1, cntn, deg2, src, n, base);
  int t = threadIdx.x;
  int i0 = base + t * 4;
  int s = 0;
  if (i0 + 3 < n){ int4 v = *(const int4*)&src[i0]; s = v.x + v.y + v.z + v.w; }
  else { for (int j = 0; j < 4; ++j){ int i = i0 + j; if (i < n) s += src[i]; } }
  __shared__ int sh[256];
  sh[t] = s; __syncthreads();
  for (int off = 128; off > 0; off >>= 1){
    if (t < off) sh[t] += sh[t + off];
    __syncthreads();
  }
  if (t == 0) bsum[b] = sh[0];
}

__launch_bounds__(256)
__global__ void scan_bsums(const int* __restrict__ bsum, int* __restrict__ boff,
                           int* __restrict__ rowptr1, int* __restrict__ rowptrn,
                           int* __restrict__ rowptr2){
  __shared__ int s[256];
  int t = threadIdx.x;
  int v = (t < NBT) ? bsum[t] : 0;
  s[t] = v; __syncthreads();
  int seg = (t < NB1) ? 0 : (t < NB1 + NB2 ? 1 : 2);
  for (int off = 1; off < 256; off <<= 1){
    int add = 0;
    if (t >= off){
      int u = t - off;
      int useg = (u < NB1) ? 0 : (u < NB1 + NB2 ? 1 : 2);
      if (useg == seg) add = s[u];
    }
    __syncthreads();
    s[t] += add;
    __syncthreads();
  }
  if (t < NBT) boff[t] = s[t] - v;
  if (t == NB1 - 1)       rowptr1[N_NODES] = s[t];
  if (t == NB1 + NB2 - 1) rowptrn[N_CLUST] = s[t];
  if (t == NBT - 1)       rowptr2[N_CLUST] = s[t];
}

__launch_bounds__(256)
__global__ void scan_final(const int* __restrict__ deg1, const int* __restrict__ cntn,
                           const int* __restrict__ deg2, const int* __restrict__ boff,
                           int* __restrict__ rowptr1, float* __restrict__ dis1,
                           int* __restrict__ rowptrn, int* __restrict__ curn,
                           int* __restrict__ rowptr2, float* __restrict__ dis2){
  int b = blockIdx.x;
  const int* src; int n, base;
  seg_select(b, deg1, cntn, deg2, src, n, base);
  int* rp; int* cur; float* dis;
  if (b < NB1){ rp = rowptr1; cur = nullptr; dis = dis1; }
  else if (b < NB1 + NB2){ rp = rowptrn; cur = curn; dis = nullptr; }
  else { rp = rowptr2; cur = nullptr; dis = dis2; }
  int t = threadIdx.x;
  int i0 = base + t * 4;
  int v[4]; int s = 0;
  #pragma unroll
  for (int j = 0; j < 4; ++j){ int i = i0 + j; v[j] = (i < n) ? src[i] : 0; s += v[j]; }
  __shared__ int sh[256];
  sh[t] = s; __syncthreads();
  for (int off = 1; off < 256; off <<= 1){
    int add = (t >= off) ? sh[t - off] : 0;
    __syncthreads();
    sh[t] += add;
    __syncthreads();
  }
  int run = sh[t] - s + boff[b];
  #pragma unroll
  for (int j = 0; j < 4; ++j){
    int i = i0 + j;
    if (i < n){
      rp[i] = run;
      if (cur) cur[i] = run;
      if (dis) dis[i] = rsqrtf((float)v[j] + 1.0f);
      run += v[j];
    }
  }
}

// node->cluster CSR fill
__global__ void fill_n(const int* __restrict__ cluster, int* __restrict__ curn,
                       int* __restrict__ nidx){
  int v = blockIdx.x * blockDim.x + threadIdx.x;
  if (v >= N_NODES) return;
  nidx[atomicAdd(&curn[cluster[v]], 1)] = v;
}

// ---------------------------------------------------------------------------
// psrcC build: cluster c's pooled-edge list = concat of members' edge runs
// payload: src-cluster | (dst-cluster & 15) << 17
// ---------------------------------------------------------------------------
__launch_bounds__(256)
__global__ void psrc_build(const int* __restrict__ rowptrn, const int* __restrict__ nidx,
                           const int* __restrict__ rowptr1, const int* __restrict__ esrc1,
                           const int* __restrict__ cluster, const int* __restrict__ rowptr2,
                           int* __restrict__ psrcC){
  int c = blockIdx.x * 4 + (threadIdx.x >> 6);
  int l = threadIdx.x & 63;
  int mb = rowptrn[c], me = rowptrn[c + 1];
  int cnt = me - mb;                       // members per cluster (<= 64)
  int base_l = 0, d_l = 0;
  if (l < cnt){
    int v = nidx[mb + l];
    base_l = rowptr1[v];
    d_l = rowptr1[v + 1] - base_l;
  }
  int pref = d_l;                          // inclusive scan over 64 lanes
  #pragma unroll
  for (int off = 1; off < 64; off <<= 1){
    int u = __shfl_up(pref, off);
    if (l >= off) pref += u;
  }
  int total = __shfl(pref, 63);
  int wbase = rowptr2[c];
  int dbits = (c & 15) << 17;
  int iters = (total + 63) >> 6;           // uniform loop; all lanes active
  for (int k = 0; k < iters; ++k){
    int idx = k * 64 + l;
    int idxc = min(idx, total - 1);
    int m = 0;
    for (int j = 0; j < cnt; ++j){
      int pj = __shfl(pref, j);
      if (idxc >= pj) m = j + 1;
    }
    int pm = __shfl(pref, m);
    int dm = __shfl(d_l, m);
    int bm = __shfl(base_l, m);
    int e = bm + idxc - (pm - dm);
    int sc = cluster[esrc1[e] & (int)PAY_SRC_MASK];
    if (idx < total) psrcC[wbase + idx] = sc | dbits;
  }
}

// ---------------------------------------------------------------------------
// MFMA GEMM: C[M,128] = (A[M,128] @ B[128,128]) * scale[row], bf16 packed out
// ---------------------------------------------------------------------------
template<bool A_BF16>
__launch_bounds__(256)
__global__ void gemm_mfma(const void* __restrict__ Aptr, const float* __restrict__ B,
                          const float* __restrict__ scale, unsigned* __restrict__ Cmat,
                          int M){
  __shared__ __align__(16) unsigned Blds[128 * 68];
  __shared__ __align__(16) unsigned Alds[64 * 68];
  const int t = threadIdx.x;
  const int row0 = blockIdx.x * 64;

  #pragma unroll
  for (int i = 0; i < 8; ++i){
    int task = t + i * 256;
    int kp = task >> 5, nq = task & 31;
    float4 b0 = *(const float4*)&B[(2 * kp) * 128 + nq * 4];
    float4 b1 = *(const float4*)&B[(2 * kp + 1) * 128 + nq * 4];
    Blds[(nq * 4 + 0) * 68 + kp] = pack2(b0.x, b1.x);
    Blds[(nq * 4 + 1) * 68 + kp] = pack2(b0.y, b1.y);
    Blds[(nq * 4 + 2) * 68 + kp] = pack2(b0.z, b1.z);
    Blds[(nq * 4 + 3) * 68 + kp] = pack2(b0.w, b1.w);
  }
  if (A_BF16){
    const unsigned* A = (const unsigned*)Aptr;
    #pragma unroll
    for (int i = 0; i < 8; ++i){
      int idx = t + i * 256;
      int row = idx >> 5, c2 = idx & 31;
      int grow = min(row0 + row, M - 1);
      uint2 v = *(const uint2*)&A[(size_t)grow * 64 + c2 * 2];
      Alds[row * 68 + c2 * 2]     = v.x;
      Alds[row * 68 + c2 * 2 + 1] = v.y;
    }
  } else {
    const float* A = (const float*)Aptr;
    #pragma unroll
    for (int i = 0; i < 8; ++i){
      int idx = t + i * 256;
      int row = idx >> 5, k4 = idx & 31;
      int grow = min(row0 + row, M - 1);
      float4 v = *(const float4*)&A[(size_t)grow * 128 + k4 * 4];
      Alds[row * 68 + k4 * 2]     = pack2(v.x, v.y);
      Alds[row * 68 + k4 * 2 + 1] = pack2(v.z, v.w);
    }
  }
  __syncthreads();

  const int wv = t >> 6, l = t & 63, quad = l >> 4, n16 = l & 15;
  f32x4 acc[8];
  #pragma unroll
  for (int nt = 0; nt < 8; ++nt) acc[nt] = (f32x4){0.f, 0.f, 0.f, 0.f};
  const int arow = wv * 16 + n16;
  #pragma unroll
  for (int ks = 0; ks < 4; ++ks){
    bf16x8 af = *(const bf16x8*)&Alds[arow * 68 + ks * 16 + quad * 4];
    #pragma unroll
    for (int nt = 0; nt < 8; ++nt){
      bf16x8 bfr = *(const bf16x8*)&Blds[(nt * 16 + n16) * 68 + ks * 16 + quad * 4];
      acc[nt] = __builtin_amdgcn_mfma_f32_16x16x32_bf16(af, bfr, acc[nt], 0, 0, 0);
    }
  }
  #pragma unroll
  for (int nt = 0; nt < 8; ++nt){
    #pragma unroll
    for (int r = 0; r < 4; ++r){
      int row = row0 + wv * 16 + quad * 4 + r;
      float sc = scale[min(row, M - 1)];
      float v = acc[nt][r] * sc;
      float vhi = __shfl_xor(v, 1);
      if (((l & 1) == 0) && row < M)
        Cmat[(size_t)row * 64 + nt * 8 + (n16 >> 1)] = pack2(v, vhi);
    }
  }
}

// ---------------------------------------------------------------------------
// CSR conv, quarter-wave uint4 gather: lane l handles uint4 q=l&15 of edge
// j+(l>>4). One dwordx4 load serves 4 edges (1 KB/wave-instruction).
// 16-edge main step: 4 batched uint4 loads in flight before the dependent
// unpack/add chain (round-4 ILP fix; round-0 issued only 2).
// out[i] = relu( dis[i]*(sum_e Ts[src_e] + Ts[i]) + b )
// ---------------------------------------------------------------------------
__launch_bounds__(256)
__global__ void conv_csr(const unsigned* __restrict__ Ts, const float* __restrict__ dis,
                         const int* __restrict__ rowptr, const int* __restrict__ esrc,
                         const float* __restrict__ bias, unsigned* __restrict__ Hout){
  int w = blockIdx.x * 4 + (threadIdx.x >> 6);
  int l = threadIdx.x & 63;
  int q = l & 15, h = l >> 4;
  int beg = rowptr[w], end = rowptr[w + 1];
  float acc[8] = {0.f,0.f,0.f,0.f,0.f,0.f,0.f,0.f};
  for (int base = beg; base < end; base += 64){
    int n = min(64, end - base);
    int eid = esrc[base + min(l, n - 1)] & (int)PAY_SRC_MASK;
    int j = 0;
    for (; j + 16 <= n; j += 16){
      int s0 = __shfl(eid, j + h);
      int s1 = __shfl(eid, j + 4 + h);
      int s2 = __shfl(eid, j + 8 + h);
      int s3 = __shfl(eid, j + 12 + h);
      uint4 u0 = *(const uint4*)&Ts[(size_t)s0 * 64 + q * 4];
      uint4 u1 = *(const uint4*)&Ts[(size_t)s1 * 64 + q * 4];
      uint4 u2 = *(const uint4*)&Ts[(size_t)s2 * 64 + q * 4];
      uint4 u3 = *(const uint4*)&Ts[(size_t)s3 * 64 + q * 4];
      acc[0] += bf16lo(u0.x); acc[1] += bf16hi(u0.x);
      acc[2] += bf16lo(u0.y); acc[3] += bf16hi(u0.y);
      acc[4] += bf16lo(u0.z); acc[5] += bf16hi(u0.z);
      acc[6] += bf16lo(u0.w); acc[7] += bf16hi(u0.w);
      acc[0] += bf16lo(u1.x); acc[1] += bf16hi(u1.x);
      acc[2] += bf16lo(u1.y); acc[3] += bf16hi(u1.y);
      acc[4] += bf16lo(u1.z); acc[5] += bf16hi(u1.z);
      acc[6] += bf16lo(u1.w); acc[7] += bf16hi(u1.w);
      acc[0] += bf16lo(u2.x); acc[1] += bf16hi(u2.x);
      acc[2] += bf16lo(u2.y); acc[3] += bf16hi(u2.y);
      acc[4] += bf16lo(u2.z); acc[5] += bf16hi(u2.z);
      acc[6] += bf16lo(u2.w); acc[7] += bf16hi(u2.w);
      acc[0] += bf16lo(u3.x); acc[1] += bf16hi(u3.x);
      acc[2] += bf16lo(u3.y); acc[3] += bf16hi(u3.y);
      acc[4] += bf16lo(u3.z); acc[5] += bf16hi(u3.z);
      acc[6] += bf16lo(u3.w); acc[7] += bf16hi(u3.w);
    }
    for (; j + 8 <= n; j += 8){
      int s0 = __shfl(eid, j + h);
      int s1 = __shfl(eid, j + 4 + h);
      uint4 u0 = *(const uint4*)&Ts[(size_t)s0 * 64 + q * 4];
      uint4 u1 = *(const uint4*)&Ts[(size_t)s1 * 64 + q * 4];
      acc[0] += bf16lo(u0.x); acc[1] += bf16hi(u0.x);
      acc[2] += bf16lo(u0.y); acc[3] += bf16hi(u0.y);
      acc[4] += bf16lo(u0.z); acc[5] += bf16hi(u0.z);
      acc[6] += bf16lo(u0.w); acc[7] += bf16hi(u0.w);
      acc[0] += bf16lo(u1.x); acc[1] += bf16hi(u1.x);
      acc[2] += bf16lo(u1.y); acc[3] += bf16hi(u1.y);
      acc[4] += bf16lo(u1.z); acc[5] += bf16hi(u1.z);
      acc[6] += bf16lo(u1.w); acc[7] += bf16hi(u1.w);
    }
    for (; j < n; j += 4){
      int ei = j + h;
      int s = __shfl(eid, min(ei, n - 1));
      uint4 u = *(const uint4*)&Ts[(size_t)s * 64 + q * 4];
      if (ei < n){
        acc[0] += bf16lo(u.x); acc[1] += bf16hi(u.x);
        acc[2] += bf16lo(u.y); acc[3] += bf16hi(u.y);
        acc[4] += bf16lo(u.z); acc[5] += bf16hi(u.z);
        acc[6] += bf16lo(u.w); acc[7] += bf16hi(u.w);
      }
    }
  }
  // cross-quarter reduction: quarters hold disjoint edge subsets, same features
  #pragma unroll
  for (int k = 0; k < 8; ++k){
    acc[k] += __shfl_xor(acc[k], 16);
    acc[k] += __shfl_xor(acc[k], 32);
  }
  float d = dis[w];
  uint4 us = *(const uint4*)&Ts[(size_t)w * 64 + q * 4];
  float4 b0 = *(const float4*)&bias[q * 8];
  float4 b1 = *(const float4*)&bias[q * 8 + 4];
  float r0 = fmaxf(fmaf(d, acc[0] + bf16lo(us.x), b0.x), 0.f);
  float r1 = fmaxf(fmaf(d, acc[1] + bf16hi(us.x), b0.y), 0.f);
  float r2 = fmaxf(fmaf(d, acc[2] + bf16lo(us.y), b0.z), 0.f);
  float r3 = fmaxf(fmaf(d, acc[3] + bf16hi(us.y), b0.w), 0.f);
  float r4 = fmaxf(fmaf(d, acc[4] + bf16lo(us.z), b1.x), 0.f);
  float r5 = fmaxf(fmaf(d, acc[5] + bf16hi(us.z), b1.y), 0.f);
  float r6 = fmaxf(fmaf(d, acc[6] + bf16lo(us.w), b1.z), 0.f);
  float r7 = fmaxf(fmaf(d, acc[7] + bf16hi(us.w), b1.w), 0.f);
  if (h == 0){
    uint4 o;
    o.x = pack2(r0, r1); o.y = pack2(r2, r3);
    o.z = pack2(r4, r5); o.w = pack2(r6, r7);
    *(uint4*)&Hout[(size_t)w * 64 + q * 4] = o;
  }
}

// cluster mean pool + batch_p, quarter-wave uint4 gather
__launch_bounds__(256)
__global__ void cluster_gather(const unsigned* __restrict__ h1, const int* __restrict__ rowptrn,
                               const int* __restrict__ nidx, const int* __restrict__ batch,
                               unsigned* __restrict__ hp, int* __restrict__ batchp){
  int c = blockIdx.x * 4 + (threadIdx.x >> 6);
  int l = threadIdx.x & 63;
  int q = l & 15, h = l >> 4;
  int mb = rowptrn[c], me = rowptrn[c + 1];
  float acc[8] = {0.f,0.f,0.f,0.f,0.f,0.f,0.f,0.f};
  int vmax = -1;
  for (int base = mb; base < me; base += 64){
    int n = min(64, me - base);
    int vid = nidx[base + min(l, n - 1)];
    if (l < n) vmax = max(vmax, vid);
    int j = 0;
    for (; j + 8 <= n; j += 8){
      int s0 = __shfl(vid, j + h);
      int s1 = __shfl(vid, j + 4 + h);
      uint4 u0 = *(const uint4*)&h1[(size_t)s0 * 64 + q * 4];
      uint4 u1 = *(const uint4*)&h1[(size_t)s1 * 64 + q * 4];
      acc[0] += bf16lo(u0.x); acc[1] += bf16hi(u0.x);
      acc[2] += bf16lo(u0.y); acc[3] += bf16hi(u0.y);
      acc[4] += bf16lo(u0.z); acc[5] += bf16hi(u0.z);
      acc[6] += bf16lo(u0.w); acc[7] += bf16hi(u0.w);
      acc[0] += bf16lo(u1.x); acc[1] += bf16hi(u1.x);
      acc[2] += bf16lo(u1.y); acc[3] += bf16hi(u1.y);
      acc[4] += bf16lo(u1.z); acc[5] += bf16hi(u1.z);
      acc[6] += bf16lo(u1.w); acc[7] += bf16hi(u1.w);
    }
    for (; j < n; j += 4){
      int ei = j + h;
      int s = __shfl(vid, min(ei, n - 1));
      uint4 u = *(const uint4*)&h1[(size_t)s * 64 + q * 4];
      if (ei < n){
        acc[0] += bf16lo(u.x); acc[1] += bf16hi(u.x);
        acc[2] += bf16lo(u.y); acc[3] += bf16hi(u.y);
        acc[4] += bf16lo(u.z); acc[5] += bf16hi(u.z);
        acc[6] += bf16lo(u.w); acc[7] += bf16hi(u.w);
      }
    }
  }
  #pragma unroll
  for (int k = 0; k < 8; ++k){
    acc[k] += __shfl_xor(acc[k], 16);
    acc[k] += __shfl_xor(acc[k], 32);
  }
  #pragma unroll
  for (int off = 32; off > 0; off >>= 1) vmax = max(vmax, __shfl_xor(vmax, off));
  float inv = 1.0f / (float)max(me - mb, 1);
  if (h == 0){
    uint4 o;
    o.x = pack2(acc[0] * inv, acc[1] * inv);
    o.y = pack2(acc[2] * inv, acc[3] * inv);
    o.z = pack2(acc[4] * inv, acc[5] * inv);
    o.w = pack2(acc[6] * inv, acc[7] * inv);
    *(uint4*)&hp[(size_t)c * 64 + q * 4] = o;
  }
  if (l == 0) batchp[c] = (vmax >= 0) ? batch[vmax] : 0;  // batch sorted by node id
}

__global__ void cntp_kernel(const int* __restrict__ batchp, int* __restrict__ cntp){
  int c = blockIdx.x * blockDim.x + threadIdx.x;
  if (c < N_CLUST) atomicAdd(&cntp[batchp[c]], 1);
}

// graph -> cluster CSR: scan cntp (64 entries) + cursor fill
__global__ void scan_cntp(const int* __restrict__ cntp, int* __restrict__ gbasep,
                          int* __restrict__ curp){
  int t = threadIdx.x;                 // 64 threads
  int v = cntp[t];
  int s = v;
  for (int off = 1; off < 64; off <<= 1){
    int u = __shfl_up(s, off);
    if (t >= off) s += u;
  }
  gbasep[t] = s - v; curp[t] = s - v;
  if (t == 63) gbasep[64] = s;
}

__global__ void fill_c(const int* __restrict__ batchp, int* __restrict__ curp,
                       int* __restrict__ cidx){
  int c = blockIdx.x * blockDim.x + threadIdx.x;
  if (c < N_CLUST) cidx[atomicAdd(&curp[batchp[c]], 1)] = c;
}

// ---------------------------------------------------------------------------
__global__ void graph_bounds(const int* __restrict__ batch, int* __restrict__ gstart){
  int g = threadIdx.x;
  if (g > N_GRAPH) return;
  int lo = 0, hi = N_NODES;
  while (lo < hi){ int mid = (lo + hi) >> 1; if (batch[mid] < g) lo = mid + 1; else hi = mid; }
  gstart[g] = lo;
}

__device__ __forceinline__ void atomicMaxPosF(float* addr, float v){
  atomicMax((int*)addr, __float_as_int(v));
}

// pre-pool gather: graph g's rows are contiguous [gstart[g], gstart[g+1])
constexpr int PRE_SPLIT = 8;
__launch_bounds__(256)
__global__ void pre_pool_g(const unsigned* __restrict__ h1, const int* __restrict__ gstart,
                           float* __restrict__ psum, float* __restrict__ pmax){
  int g = blockIdx.x / PRE_SPLIT, sp = blockIdx.x % PRE_SPLIT;
  int t = threadIdx.x, w = t >> 6, l = t & 63;
  int s0 = gstart[g], s1 = gstart[g + 1];
  int n = s1 - s0;
  int per = (n + PRE_SPLIT - 1) / PRE_SPLIT;
  int b0 = s0 + sp * per, b1 = min(b0 + per, s1);
  float2 a0{0.f,0.f}, a1{0.f,0.f}, a2{0.f,0.f}, a3{0.f,0.f};
  float2 mx{0.f,0.f};
  int i = b0 + w;
  for (; i + 12 < b1; i += 16){
    unsigned u0 = h1[(size_t)(i     ) * 64 + l];
    unsigned u1 = h1[(size_t)(i +  4) * 64 + l];
    unsigned u2 = h1[(size_t)(i +  8) * 64 + l];
    unsigned u3 = h1[(size_t)(i + 12) * 64 + l];
    float f0x = bf16lo(u0), f0y = bf16hi(u0);
    float f1x = bf16lo(u1), f1y = bf16hi(u1);
    float f2x = bf16lo(u2), f2y = bf16hi(u2);
    float f3x = bf16lo(u3), f3y = bf16hi(u3);
    a0.x += f0x; a0.y += f0y; a1.x += f1x; a1.y += f1y;
    a2.x += f2x; a2.y += f2y; a3.x += f3x; a3.y += f3y;
    mx.x = fmaxf(fmaxf(mx.x, fmaxf(f0x, f1x)), fmaxf(f2x, f3x));
    mx.y = fmaxf(fmaxf(mx.y, fmaxf(f0y, f1y)), fmaxf(f2y, f3y));
  }
  for (; i < b1; i += 4){
    unsigned u = h1[(size_t)i * 64 + l];
    float fx = bf16lo(u), fy = bf16hi(u);
    a0.x += fx; a0.y += fy;
    mx.x = fmaxf(mx.x, fx); mx.y = fmaxf(mx.y, fy);
  }
  __shared__ float2 ssum[4][64], smax[4][64];
  ssum[w][l] = { a0.x + a1.x + a2.x + a3.x, a0.y + a1.y + a2.y + a3.y };
  smax[w][l] = mx;
  __syncthreads();
  if (w == 0){
    float2 S = ssum[0][l], M = smax[0][l];
    #pragma unroll
    for (int k = 1; k < 4; ++k){
      S.x += ssum[k][l].x; S.y += ssum[k][l].y;
      M.x = fmaxf(M.x, smax[k][l].x); M.y = fmaxf(M.y, smax[k][l].y);
    }
    atomicAdd(&psum[g * 128 + 2 * l], S.x);
    atomicAdd(&psum[g * 128 + 2 * l + 1], S.y);
    atomicMaxPosF(&pmax[g * 128 + 2 * l], M.x);
    atomicMaxPosF(&pmax[g * 128 + 2 * l + 1], M.y);
  }
}

// post-pool gather via graph->cluster CSR
constexpr int POST_SPLIT = 4;
__launch_bounds__(256)
__global__ void post_pool_g(const unsigned* __restrict__ hp3, const int* __restrict__ gbasep,
                            const int* __restrict__ cidx,
                            float* __restrict__ psum, float* __restrict__ pmax){
  int g = blockIdx.x / POST_SPLIT, sp = blockIdx.x % POST_SPLIT;
  int t = threadIdx.x, w = t >> 6, l = t & 63;
  int s0 = gbasep[g], s1 = gbasep[g + 1];
  int n = s1 - s0;
  int per = (n + POST_SPLIT * 4 - 1) / (POST_SPLIT * 4);
  int b0 = s0 + (sp * 4 + w) * per, b1 = min(b0 + per, s1);
  float2 a0{0.f,0.f}, a1{0.f,0.f}, a2{0.f,0.f}, a3{0.f,0.f};
  float2 mx{0.f,0.f};
  for (int base = b0; base < b1; base += 64){
    int nn = min(64, b1 - base);
    int cid = cidx[base + min(l, nn - 1)];
    int j = 0;
    for (; j + 4 <= nn; j += 4){
      int c0 = __shfl(cid, j);
      int c1 = __shfl(cid, j + 1);
      int c2 = __shfl(cid, j + 2);
      int c3 = __shfl(cid, j + 3);
      unsigned u0 = hp3[(size_t)c0 * 64 + l];
      unsigned u1 = hp3[(size_t)c1 * 64 + l];
      unsigned u2 = hp3[(size_t)c2 * 64 + l];
      unsigned u3 = hp3[(size_t)c3 * 64 + l];
      float f0x = bf16lo(u0), f0y = bf16hi(u0);
      float f1x = bf16lo(u1), f1y = bf16hi(u1);
      float f2x = bf16lo(u2), f2y = bf16hi(u2);
      float f3x = bf16lo(u3), f3y = bf16hi(u3);
      a0.x += f0x; a0.y += f0y; a1.x += f1x; a1.y += f1y;
      a2.x += f2x; a2.y += f2y; a3.x += f3x; a3.y += f3y;
      mx.x = fmaxf(fmaxf(mx.x, fmaxf(f0x, f1x)), fmaxf(f2x, f3x));
      mx.y = fmaxf(fmaxf(mx.y, fmaxf(f0y, f1y)), fmaxf(f2y, f3y));
    }
    for (; j < nn; ++j){
      int c = __shfl(cid, j);
      unsigned u = hp3[(size_t)c * 64 + l];
      float fx = bf16lo(u), fy = bf16hi(u);
      a0.x += fx; a0.y += fy;
      mx.x = fmaxf(mx.x, fx); mx.y = fmaxf(mx.y, fy);
    }
  }
  __shared__ float2 ssum[4][64], smax[4][64];
  ssum[w][l] = { a0.x + a1.x + a2.x + a3.x, a0.y + a1.y + a2.y + a3.y };
  smax[w][l] = mx;
  __syncthreads();
  if (w == 0){
    float2 S = ssum[0][l], M = smax[0][l];
    #pragma unroll
    for (int k = 1; k < 4; ++k){
      S.x += ssum[k][l].x; S.y += ssum[k][l].y;
      M.x = fmaxf(M.x, smax[k][l].x); M.y = fmaxf(M.y, smax[k][l].y);
    }
    atomicAdd(&psum[g * 128 + 2 * l], S.x);
    atomicAdd(&psum[g * 128 + 2 * l + 1], S.y);
    atomicMaxPosF(&pmax[g * 128 + 2 * l], M.x);
    atomicMaxPosF(&pmax[g * 128 + 2 * l + 1], M.y);
  }
}

__launch_bounds__(128)
__global__ void head_kernel(const float* __restrict__ psum, const float* __restrict__ pmax,
                            const float* __restrict__ postsum, const float* __restrict__ postmax,
                            const int* __restrict__ gstart, const int* __restrict__ cntp,
                            const float* __restrict__ l1w, const float* __restrict__ l1b,
                            const float* __restrict__ l2w, const float* __restrict__ l2b,
                            float* __restrict__ out){
  int g = blockIdx.x, t = threadIdx.x;
  __shared__ float z[512];
  __shared__ float a[128];
  __shared__ float logits[16];
  __shared__ float lse_s;
  float cpre  = (float)max(gstart[g + 1] - gstart[g], 1);
  float cpost = fmaxf((float)cntp[g], 1.0f);
  z[t]       = psum[g * 128 + t] / cpre;
  z[128 + t] = pmax[g * 128 + t];
  z[256 + t] = postsum[g * 128 + t] / cpost;
  z[384 + t] = postmax[g * 128 + t];
  __syncthreads();
  float acc = l1b[t];
  #pragma unroll 8
  for (int k = 0; k < 512; ++k) acc = fmaf(z[k], l1w[k * 128 + t], acc);
  a[t] = fmaxf(acc, 0.f);
  __syncthreads();
  if (t < NCLSN){
    float s2 = l2b[t];
    for (int k = 0; k < 128; ++k) s2 = fmaf(a[k], l2w[k * NCLSN + t], s2);
    logits[t] = s2;
  }
  __syncthreads();
  if (t == 0){
    float m = logits[0];
    for (int c = 1; c < NCLSN; ++c) m = fmaxf(m, logits[c]);
    float s = 0.f;
    for (int c = 0; c < NCLSN; ++c) s += expf(logits[c] - m);
    lse_s = m + logf(s);
  }
  __syncthreads();
  if (t < NCLSN) out[g * NCLSN + t] = logits[t] - lse_s;
}

// ---------------------------------------------------------------------------
extern "C" void kernel_launch(void* const* d_in, const int* in_sizes, int n_in,
                              void* d_out, int out_size, void* d_ws, size_t ws_size,
                              hipStream_t stream){
  const float* x       = (const float*)d_in[0];
  const int*   ei      = (const int*)  d_in[1];
  const int*   batch   = (const int*)  d_in[2];
  const int*   cluster = (const int*)  d_in[3];
  const float* W1      = (const float*)d_in[6];
  const float* b1      = (const float*)d_in[7];
  const float* W2      = (const float*)d_in[8];
  const float* b2      = (const float*)d_in[9];
  const float* W3      = (const float*)d_in[10];
  const float* b3      = (const float*)d_in[11];
  const float* l1w     = (const float*)d_in[12];
  const float* l1b     = (const float*)d_in[13];
  const float* l2w     = (const float*)d_in[14];
  const float* l2b     = (const float*)d_in[15];
  float* out = (float*)d_out;

  char* base = (char*)d_ws;
  size_t off = 0;
  auto alloc = [&](size_t bytes) -> char* {
    char* p = base + off;
    off += (bytes + 255) & ~size_t(255);
    return p;
  };
  // ---- zero zone (one memset) ----
  char*  zbase  = base + off;
  int*   cntn   = (int*)  alloc((size_t)N_CLUST * 4);
  int*   deg2   = (int*)  alloc((size_t)N_CLUST * 4);
  int*   cntp   = (int*)  alloc((size_t)N_GRAPH * 4);
  float* pre_s  = (float*)alloc((size_t)N_GRAPH * 128 * 4);
  float* pre_m  = (float*)alloc((size_t)N_GRAPH * 128 * 4);
  float* post_s = (float*)alloc((size_t)N_GRAPH * 128 * 4);
  float* post_m = (float*)alloc((size_t)N_GRAPH * 128 * 4);
  size_t zsize = off;
  // ---- plain buffers (bf16 feature rows: 64 uints per row) ----
  unsigned* Ts1   = (unsigned*)alloc((size_t)N_NODES * 64 * 4);  // later aliased
  unsigned* h1    = (unsigned*)alloc((size_t)N_NODES * 64 * 4);  // stage buf aliases here
  int*   esrc1   = (int*)  alloc((size_t)N_EDGES * 4);
  int*   psrcC   = (int*)  alloc((size_t)N_EDGES * 4);
  int*   deg1    = (int*)  alloc((size_t)N_NODES * 4);
  int*   rowptr1 = (int*)  alloc((size_t)(N_NODES + 1) * 4);
  int*   rowptrn = (int*)  alloc((size_t)(N_CLUST + 1) * 4);
  int*   curn    = (int*)  alloc((size_t)N_CLUST * 4);
  int*   rowptr2 = (int*)  alloc((size_t)(N_CLUST + 1) * 4);
  int*   nidx    = (int*)  alloc((size_t)N_NODES * 4);
  float* dis1    = (float*)alloc((size_t)N_NODES * 4);
  float* dis2    = (float*)alloc((size_t)N_CLUST * 4);
  int*   batchp  = (int*)  alloc((size_t)N_CLUST * 4);
  int*   gstart  = (int*)  alloc((size_t)(N_GRAPH + 1) * 4);
  int*   bsum    = (int*)  alloc((size_t)NBT * 4);
  int*   boff    = (int*)  alloc((size_t)NBT * 4);
  int*   gcnt1   = (int*)  alloc((size_t)NBKT1 * 4);
  int*   gbase1  = (int*)  alloc((size_t)NBKT1 * 4);
  int*   bhist   = (int*)  alloc((size_t)NEB * NBKT1 * 4);
  int*   boffs   = (int*)  alloc((size_t)NEB * NBKT1 * 4);
  int*   gbasep  = (int*)  alloc((size_t)(N_GRAPH + 1) * 4);
  int*   curp    = (int*)  alloc((size_t)N_GRAPH * 4);
  int*   cidx    = (int*)  alloc((size_t)N_CLUST * 4);
  // stage buffer aliases the (not-yet-written) h1 region (6.4 MB <= 25.6 MB)
  unsigned int* stage1 = (unsigned int*)h1;
  // aliases into Ts1 (dead after conv1): 4 x 25000*64 uints = exactly Ts1 size
  unsigned* hp  = Ts1;
  unsigned* Ts2 = Ts1 + (size_t)N_CLUST * 64;
  unsigned* hp2 = Ts1 + (size_t)2 * N_CLUST * 64;
  unsigned* hp3 = Ts1 + (size_t)3 * N_CLUST * 64;
  unsigned* Ts3 = Ts2;

  (void)in_sizes; (void)n_in; (void)out_size; (void)ws_size;

  hipMemsetAsync(zbase, 0, zsize, stream);

  // ---- radix node-CSR build ----
  count_kernel  <<<NEB, 1024, 0, stream>>>(ei, bhist);
  colscan       <<<NBKT1, 512, 0, stream>>>(bhist, boffs, gcnt1);
  bucket_scan   <<<1, 256, 0, stream>>>(gcnt1, gbase1);
  scatter_kernel<<<NEB, 1024, 0, stream>>>(ei, gbase1, boffs, stage1);
  bucket_sort   <<<NBKT1, 1024, 0, stream>>>(stage1, gbase1, gcnt1, esrc1, deg1);
  node_prep<<<(N_NODES + 255) / 256, 256, 0, stream>>>(cluster, deg1, cntn, deg2);
  block_sums <<<NBT, 256, 0, stream>>>(deg1, cntn, deg2, bsum);
  scan_bsums <<<1, 256, 0, stream>>>(bsum, boff, rowptr1, rowptrn, rowptr2);
  scan_final <<<NBT, 256, 0, stream>>>(deg1, cntn, deg2, boff,
                                       rowptr1, dis1, rowptrn, curn, rowptr2, dis2);
  fill_n<<<(N_NODES + 255) / 256, 256, 0, stream>>>(cluster, curn, nidx);
  psrc_build<<<N_CLUST / 4, 256, 0, stream>>>(rowptrn, nidx, rowptr1, esrc1,
                                              cluster, rowptr2, psrcC);

  // conv1
  gemm_mfma<false><<<(N_NODES + 63) / 64, 256, 0, stream>>>(x, W1, dis1, Ts1, N_NODES);
  conv_csr<<<N_NODES / 4, 256, 0, stream>>>(Ts1, dis1, rowptr1, esrc1, b1, h1);

  // pre pools (gather over contiguous sorted-batch ranges)
  graph_bounds<<<1, 128, 0, stream>>>(batch, gstart);
  pre_pool_g<<<N_GRAPH * PRE_SPLIT, 256, 0, stream>>>(h1, gstart, pre_s, pre_m);

  // cluster mean pool + batch_p + cntp + graph->cluster CSR
  cluster_gather<<<N_CLUST / 4, 256, 0, stream>>>(h1, rowptrn, nidx, batch, hp, batchp);
  cntp_kernel<<<(N_CLUST + 255) / 256, 256, 0, stream>>>(batchp, cntp);
  scan_cntp<<<1, 64, 0, stream>>>(cntp, gbasep, curp);
  fill_c<<<(N_CLUST + 255) / 256, 256, 0, stream>>>(batchp, curp, cidx);

  // conv2
  gemm_mfma<true><<<(N_CLUST + 63) / 64, 256, 0, stream>>>(hp, W2, dis2, Ts2, N_CLUST);
  conv_csr<<<N_CLUST / 4, 256, 0, stream>>>(Ts2, dis2, rowptr2, psrcC, b2, hp2);

  // conv3
  gemm_mfma<true><<<(N_CLUST + 63) / 64, 256, 0, stream>>>(hp2, W3, dis2, Ts3, N_CLUST);
  conv_csr<<<N_CLUST / 4, 256, 0, stream>>>(Ts3, dis2, rowptr2, psrcC, b3, hp3);

  // post pools (gather via graph->cluster CSR) + head
  post_pool_g<<<N_GRAPH * POST_SPLIT, 256, 0, stream>>>(hp3, gbasep, cidx, post_s, post_m);
  head_kernel<<<N_GRAPH, 128, 0, stream>>>(pre_s, pre_m, post_s, post_m, gstart, cntp,
                                           l1w, l1b, l2w, l2b, out);
}